// Round 6
// baseline (144.371 us; speedup 1.0000x reference)
//
#include <hip/hip_runtime.h>

#define N_B   2048
#define F_SIG 1056
#define F_PAD 1088
#define K_CLS 100
#define K_PAD 128
#define KW_PAD 104         // k rows allocated in part[] (13 y-blocks x 8)
#define DROW   52          // 49 real + 3 pad, 16B-aligned rows
#define OSPLIT  8
#define OCHUNK 132
#define XW     72          // ushorts per padded-position row (16B-mult, bank-spread)
#define SY     16          // k_stats partial row-groups
#define IHALF  528         // k_out i-split

typedef __attribute__((ext_vector_type(8))) short s8v;     // 8 bf16 in 4 VGPRs
typedef __attribute__((ext_vector_type(4))) float f4v;

__device__ __host__ __forceinline__ void split_bf16(float x, unsigned& h, unsigned& l) {
    unsigned u = __builtin_bit_cast(unsigned, x);
    unsigned hb = (u + 0x7FFFu + ((u >> 16) & 1u)) >> 16;
    float hf = __builtin_bit_cast(float, hb << 16);
    float r = x - hf;
    unsigned ur = __builtin_bit_cast(unsigned, r);
    unsigned lb = (ur + 0x7FFFu + ((ur >> 16) & 1u)) >> 16;
    h = hb & 0xFFFFu; l = lb & 0xFFFFu;
}

// ---------- prepack conv weights into MFMA A-fragments (hi/lo split) ----------
// frag f = ((tap*2+ch)*2+mt); element (lane,e): oc = mt*16+(lane&15),
// cin = ch*32+(lane>>4)*8+e, value = cw[oc][cin][tap]   (layout verified R4)
__global__ void k_wt(const float* __restrict__ cw, unsigned short* __restrict__ Ahi,
                     unsigned short* __restrict__ Alo) {
    int t = blockIdx.x * 256 + threadIdx.x;
    if (t >= 36 * 512) return;
    int f = t >> 9, r = t & 511, lane = r >> 3, e = r & 7;
    int mt = f & 1, ch = (f >> 1) & 1, tap = f >> 2;
    int oc  = mt * 16 + (lane & 15);
    int cin = ch * 32 + (lane >> 4) * 8 + e;
    float v = cw[oc * 576 + cin * 9 + tap];
    unsigned h, l;
    split_bf16(v, h, l);
    Ahi[t] = (unsigned short)h;
    Alo[t] = (unsigned short)l;
}

// ---------- MFMA conv(64->32,3x3,pad1) + Zhang signature depth-2, one image/block ----------
__launch_bounds__(256, 4)
__global__ void k_convsig(const float* __restrict__ x,
                          const unsigned short* __restrict__ Ahi,
                          const unsigned short* __restrict__ Alo,
                          float* __restrict__ sig) {
    __shared__ __align__(16) unsigned short xhi[100 * XW];   // [pad_pos][cin] hi-plane
    __shared__ __align__(16) unsigned short xlo[100 * XW];   // lo-plane
    __shared__ __align__(16) float ysT[64 * 36];             // [pos][oc] stride 36
    float* Ds   = (float*)xhi;          // 32*52   (x planes dead after conv)
    float* Cs   = Ds + 1664;            // 32*52   in-place -> strict 2D prefix P
    float* colS = Cs + 1664;            // 32*8    column sums for level-1
    const int tid = threadIdx.x;
    const int b = blockIdx.x;

    // --- stage: zero planes, then split/scatter feats (position-major) ---
    {
        unsigned* zh = (unsigned*)xhi;
        unsigned* zl = (unsigned*)xlo;
        for (int e = tid; e < 100 * XW / 2; e += 256) { zh[e] = 0u; zl[e] = 0u; }
    }
    __syncthreads();
    const float4* xb4 = reinterpret_cast<const float4*>(x + (size_t)b * 4096);
    for (int e = tid; e < 1024; e += 256) {
        float4 v = xb4[e];
        int cin = e >> 4, p = (e & 15) * 4;
        int ih = p >> 3, iw = p & 7;                   // iw in {0,4}
        int pp = (ih + 1) * 10 + (iw + 1);
        unsigned h, l;
        split_bf16(v.x, h, l); xhi[(pp+0)*XW + cin] = (unsigned short)h; xlo[(pp+0)*XW + cin] = (unsigned short)l;
        split_bf16(v.y, h, l); xhi[(pp+1)*XW + cin] = (unsigned short)h; xlo[(pp+1)*XW + cin] = (unsigned short)l;
        split_bf16(v.z, h, l); xhi[(pp+2)*XW + cin] = (unsigned short)h; xlo[(pp+2)*XW + cin] = (unsigned short)l;
        split_bf16(v.w, h, l); xhi[(pp+3)*XW + cin] = (unsigned short)h; xlo[(pp+3)*XW + cin] = (unsigned short)l;
    }
    __syncthreads();

    // --- MFMA conv: wave = one n-tile of 16 positions, 32 oc ---
    {
        const int wv = tid >> 6;
        const int lane = tid & 63;
        const int j16 = lane & 15, kg = lane >> 4;
        const int p2 = wv * 16 + j16;
        const int oh = p2 >> 3, ow = p2 & 7;
        const unsigned short* Hb = xhi + (oh * 10 + ow) * XW + kg * 8;
        const unsigned short* Lb = xlo + (oh * 10 + ow) * XW + kg * 8;
        const uint4* AH = reinterpret_cast<const uint4*>(Ahi) + lane;  // frag f at +f*64
        const uint4* AL = reinterpret_cast<const uint4*>(Alo) + lane;
        f4v acc0 = {0.f, 0.f, 0.f, 0.f};
        f4v acc1 = {0.f, 0.f, 0.f, 0.f};
#pragma unroll
        for (int k = 0; k < 18; ++k) {
            const int tap = k >> 1, ch = k & 1;
            const int th = tap / 3, tw = tap % 3;          // fold at compile time
            const int xoff = (th * 10 + tw) * XW + ch * 32;
            const int f0 = (tap * 2 + ch) * 2;
            uint4 bh = *reinterpret_cast<const uint4*>(Hb + xoff);
            uint4 bl = *reinterpret_cast<const uint4*>(Lb + xoff);
            uint4 a0h = AH[f0 * 64], a0l = AL[f0 * 64];
            uint4 a1h = AH[f0 * 64 + 64], a1l = AL[f0 * 64 + 64];
            s8v Bh = __builtin_bit_cast(s8v, bh);
            s8v Bl = __builtin_bit_cast(s8v, bl);
            s8v A0h = __builtin_bit_cast(s8v, a0h);
            s8v A0l = __builtin_bit_cast(s8v, a0l);
            s8v A1h = __builtin_bit_cast(s8v, a1h);
            s8v A1l = __builtin_bit_cast(s8v, a1l);
            acc0 = __builtin_amdgcn_mfma_f32_16x16x32_bf16(A0h, Bh, acc0, 0, 0, 0);
            acc0 = __builtin_amdgcn_mfma_f32_16x16x32_bf16(A0h, Bl, acc0, 0, 0, 0);
            acc0 = __builtin_amdgcn_mfma_f32_16x16x32_bf16(A0l, Bh, acc0, 0, 0, 0);
            acc1 = __builtin_amdgcn_mfma_f32_16x16x32_bf16(A1h, Bh, acc1, 0, 0, 0);
            acc1 = __builtin_amdgcn_mfma_f32_16x16x32_bf16(A1h, Bl, acc1, 0, 0, 0);
            acc1 = __builtin_amdgcn_mfma_f32_16x16x32_bf16(A1l, Bh, acc1, 0, 0, 0);
        }
        // C/D: col=lane&15 -> pos, row=(lane>>4)*4+reg -> oc
        *reinterpret_cast<f4v*>(ysT + p2 * 36 + kg * 4)      = acc0;
        *reinterpret_cast<f4v*>(ysT + p2 * 36 + 16 + kg * 4) = acc1;
    }
    __syncthreads();

    // --- fused D + strict column scan; thread = (c, j) ---
    if (tid < 224) {
        const int c = tid / 7, j = tid - (tid / 7) * 7;
        float a  = ysT[j * 36 + c];            // ys[0][j]
        float bq = ysT[(j + 1) * 36 + c];      // ys[0][j+1]
        float run = 0.f;
        float* Dc = Ds + c * DROW;
        float* Cc = Cs + c * DROW;
#pragma unroll
        for (int i = 0; i < 7; ++i) {
            float a2 = ysT[((i + 1) * 8 + j) * 36 + c];
            float b2 = ysT[((i + 1) * 8 + j + 1) * 36 + c];
            float d = (b2 - a2) - (bq - a);
            Dc[i * 7 + j] = d;
            Cc[i * 7 + j] = run;               // strict prefix along i
            run += d;
            a = a2; bq = b2;
        }
        colS[c * 8 + j] = run;                 // full column sum (for level-1)
    } else {
        const int c = tid - 224;               // zero D row pads
        Ds[c * DROW + 49] = 0.f; Ds[c * DROW + 50] = 0.f; Ds[c * DROW + 51] = 0.f;
    }
    __syncthreads();

    // --- in-place strict row scan: Cs becomes strict 2D prefix P; thread = (c, i) ---
    if (tid < 224) {
        const int c = tid / 7, i = tid - (tid / 7) * 7;
        float* Cc = Cs + c * DROW + i * 7;
        float run = 0.f;
#pragma unroll
        for (int j = 0; j < 7; ++j) {
            float v = Cc[j];
            Cc[j] = run;
            run += v;
        }
    } else {
        const int c = tid - 224;               // zero P row pads
        Cs[c * DROW + 49] = 0.f; Cs[c * DROW + 50] = 0.f; Cs[c * DROW + 51] = 0.f;
    }
    __syncthreads();

    // --- level-2: 2x2 register-blocked, vectorized LDS reads (P = Cs) ---
    {
        const int bc1 = tid >> 4, bc2 = tid & 15;
        const float* P0 = Cs + bc1 * DROW;
        const float* P1 = Cs + (bc1 + 16) * DROW;
        const float* D0 = Ds + bc2 * DROW;
        const float* D1 = Ds + (bc2 + 16) * DROW;
        float a00 = 0.f, a01 = 0.f, a10 = 0.f, a11 = 0.f;
#pragma unroll
        for (int qb = 0; qb < DROW; qb += 4) {
            float4 p0 = *reinterpret_cast<const float4*>(P0 + qb);
            float4 p1 = *reinterpret_cast<const float4*>(P1 + qb);
            float4 d0 = *reinterpret_cast<const float4*>(D0 + qb);
            float4 d1 = *reinterpret_cast<const float4*>(D1 + qb);
            a00 += p0.x*d0.x + p0.y*d0.y + p0.z*d0.z + p0.w*d0.w;
            a01 += p0.x*d1.x + p0.y*d1.y + p0.z*d1.z + p0.w*d1.w;
            a10 += p1.x*d0.x + p1.y*d0.y + p1.z*d0.z + p1.w*d0.w;
            a11 += p1.x*d1.x + p1.y*d1.y + p1.z*d1.z + p1.w*d1.w;
        }
        float* so = sig + (size_t)b * F_PAD + 32;
        so[bc1 * 32 + bc2]               = a00;
        so[bc1 * 32 + (bc2 + 16)]        = a01;
        so[(bc1 + 16) * 32 + bc2]        = a10;
        so[(bc1 + 16) * 32 + (bc2 + 16)] = a11;
    }

    // --- level-1 from column sums + zero sig pad ---
    if (tid < 32) {
        const float* cr = colS + tid * 8;
        float s = cr[0] + cr[1] + cr[2] + cr[3] + cr[4] + cr[5] + cr[6];
        sig[(size_t)b * F_PAD + tid] = s;
    } else if (tid < 64) {
        sig[(size_t)b * F_PAD + F_SIG + (tid - 32)] = 0.f;
    }
}

// ---------- per-feature partial sum / sumsq (no atomics, no init) ----------
__global__ void k_stats(const float* __restrict__ sig, float* __restrict__ psum,
                        float* __restrict__ psq) {
    int f = blockIdx.x * 256 + threadIdx.x;
    if (f >= F_SIG) return;
    int y = blockIdx.y;
    int r0 = y * 128;
    float s = 0.f, q = 0.f;
    for (int r = r0; r < r0 + 128; ++r) {
        float v = sig[(size_t)r * F_PAD + f];
        s += v;
        q = fmaf(v, v, q);
    }
    psum[(size_t)y * F_PAD + f] = s;
    psq[(size_t)y * F_PAD + f]  = q;
}

// ---------- BN fold (reduces the 16 partials) ----------
__global__ void k_ab(const float* __restrict__ psum, const float* __restrict__ psq,
                     const float* __restrict__ gamma, const float* __restrict__ beta,
                     float* __restrict__ Av, float* __restrict__ Bv) {
    int i = blockIdx.x * 256 + threadIdx.x;
    if (i >= F_PAD) return;
    float a = 0.f, bb = 0.f;
    if (i < F_SIG) {
        float s = 0.f, q = 0.f;
#pragma unroll
        for (int z = 0; z < SY; ++z) {
            s += psum[(size_t)z * F_PAD + i];
            q += psq[(size_t)z * F_PAD + i];
        }
        float m   = s * (1.f / 2048.f);
        float var = q * (1.f / 2048.f) - m * m;
        a  = gamma[i] / sqrtf(var + 1e-5f);
        bb = beta[i] - m * a;
    }
    Av[i] = a;
    Bv[i] = bb;
}

// ---------- t[o] = lin_b[o] + sum_i Bv[i]*lin_w[o,i] ----------
__global__ void k_t(const float* __restrict__ lw, const float* __restrict__ Bv,
                    const float* __restrict__ lb, float* __restrict__ tvec) {
    int o = blockIdx.x, tid = threadIdx.x;
    const float* lr = lw + (size_t)o * F_SIG;
    float s = 0.f;
    for (int i = tid; i < F_SIG; i += 256) s = fmaf(Bv[i], lr[i], s);
#pragma unroll
    for (int d = 32; d; d >>= 1) s += __shfl_xor(s, d);
    __shared__ float red[4];
    if ((tid & 63) == 0) red[tid >> 6] = s;
    __syncthreads();
    if (tid == 0) tvec[o] = lb[o] + red[0] + red[1] + red[2] + red[3];
}

// ---------- split-K partials: part[z][k][i] += fcw[k,o]*lin_w[o,i], 8 k per block ----------
__launch_bounds__(256)
__global__ void k_wf(const float* __restrict__ fcw, const float* __restrict__ lw,
                     float* __restrict__ part) {
    const int wv = threadIdx.x >> 6;
    const int k0 = blockIdx.y * 8 + wv * 2;         // this wave's two k rows
    const int z  = blockIdx.z;
    const int ib = blockIdx.x * 256 + (threadIdx.x & 63) * 4;
    if (ib >= F_SIG) return;
    const float* f0 = fcw + (size_t)min(k0,     K_CLS - 1) * F_SIG;
    const float* f1 = fcw + (size_t)min(k0 + 1, K_CLS - 1) * F_SIG;
    const int o0 = z * OCHUNK;
    float4 A0 = {0.f,0.f,0.f,0.f}, A1 = {0.f,0.f,0.f,0.f};
    for (int o = o0; o < o0 + OCHUNK; ++o) {
        float s0 = f0[o], s1 = f1[o];
        float4 v = *reinterpret_cast<const float4*>(lw + (size_t)o * F_SIG + ib);
        A0.x = fmaf(s0, v.x, A0.x); A0.y = fmaf(s0, v.y, A0.y);
        A0.z = fmaf(s0, v.z, A0.z); A0.w = fmaf(s0, v.w, A0.w);
        A1.x = fmaf(s1, v.x, A1.x); A1.y = fmaf(s1, v.y, A1.y);
        A1.z = fmaf(s1, v.z, A1.z); A1.w = fmaf(s1, v.w, A1.w);
    }
    *reinterpret_cast<float4*>(part + ((size_t)z * KW_PAD + k0) * F_SIG + ib)     = A0;
    *reinterpret_cast<float4*>(part + ((size_t)z * KW_PAD + k0 + 1) * F_SIG + ib) = A1;
}

// ---------- reduce partials, fold Av, emit WfT[i*128 + k] ----------
__launch_bounds__(64)
__global__ void k_wfred(const float* __restrict__ part, const float* __restrict__ Av,
                        float* __restrict__ WfT) {
    const int i = blockIdx.x * 64 + threadIdx.x;
    const int k = blockIdx.y;
    if (i >= F_SIG) return;
    float w = 0.f;
    if (k < K_CLS) {
        float s = 0.f;
#pragma unroll
        for (int z = 0; z < OSPLIT; ++z)
            s += part[((size_t)z * KW_PAD + k) * F_SIG + i];
        w = Av[i] * s;
    }
    WfT[(size_t)i * K_PAD + k] = w;
}

// ---------- bf[k] = fc_b[k] + sum_o fc_w[k,o]*t[o] ----------
__global__ void k_bf(const float* __restrict__ fcw, const float* __restrict__ tvec,
                     const float* __restrict__ fcb, float* __restrict__ bf) {
    int k = blockIdx.x, tid = threadIdx.x;
    float s = 0.f;
    if (k < K_CLS) {
        const float* fr = fcw + (size_t)k * F_SIG;
        for (int o = tid; o < F_SIG; o += 256) s = fmaf(fr[o], tvec[o], s);
    }
#pragma unroll
    for (int d = 32; d; d >>= 1) s += __shfl_xor(s, d);
    __shared__ float red[4];
    if ((tid & 63) == 0) red[tid >> 6] = s;
    __syncthreads();
    if (tid == 0) {
        float tot = red[0] + red[1] + red[2] + red[3];
        bf[k] = (k < K_CLS) ? (tot + fcb[k]) : 0.f;
    }
}

// ---------- opart[z][r][k] = sum_{i in half z} sig[r,i]*WfT[i,k]; 8 rows/block ----------
__launch_bounds__(256)
__global__ void k_out2(const float* __restrict__ sig, const float* __restrict__ WfT,
                       float* __restrict__ opart) {
    __shared__ __align__(16) float sl[8 * IHALF];
    const int tid = threadIdx.x;
    const int z  = blockIdx.x & 1;
    const int r0 = (blockIdx.x >> 1) * 8;
    const int i0 = z * IHALF;
    for (int e = tid; e < 8 * (IHALF / 4); e += 256) {
        int row = e / (IHALF / 4), c4 = e - row * (IHALF / 4);
        float4 v = *reinterpret_cast<const float4*>(sig + (size_t)(r0 + row) * F_PAD + i0 + c4 * 4);
        *reinterpret_cast<float4*>(sl + row * IHALF + c4 * 4) = v;
    }
    __syncthreads();

    const int rl = tid >> 5;          // 0..7
    const int kb = tid & 31;
    const float4* W4 = reinterpret_cast<const float4*>(WfT) + (size_t)i0 * 32 + kb;
    const float* srow = sl + rl * IHALF;
    float4 acc = {0.f, 0.f, 0.f, 0.f};
#pragma unroll 4
    for (int i = 0; i < IHALF; ++i) {
        float ss = srow[i];
        float4 w = W4[i * 32];
        acc.x = fmaf(ss, w.x, acc.x);
        acc.y = fmaf(ss, w.y, acc.y);
        acc.z = fmaf(ss, w.z, acc.z);
        acc.w = fmaf(ss, w.w, acc.w);
    }
    float4* op = reinterpret_cast<float4*>(opart);
    op[((size_t)z * N_B + r0 + rl) * 32 + kb] = acc;
}

// ---------- out[r,k] = opart[0][r][k] + opart[1][r][k] + bf[k] ----------
__launch_bounds__(256)
__global__ void k_osum(const float* __restrict__ opart, const float* __restrict__ bf,
                       float* __restrict__ out) {
    int t = blockIdx.x * 256 + threadIdx.x;
    int r = t >> 7, k = t & 127;
    if (k < K_CLS)
        out[(size_t)r * K_CLS + k] =
            opart[(size_t)r * K_PAD + k] + opart[(size_t)(N_B + r) * K_PAD + k] + bf[k];
}

extern "C" void kernel_launch(void* const* d_in, const int* in_sizes, int n_in,
                              void* d_out, int out_size, void* d_ws, size_t ws_size,
                              hipStream_t stream) {
    (void)in_sizes; (void)n_in; (void)out_size; (void)ws_size;
    const float* feats = (const float*)d_in[0];
    const float* convw = (const float*)d_in[1];
    const float* gamma = (const float*)d_in[2];
    const float* beta  = (const float*)d_in[3];
    const float* linw  = (const float*)d_in[4];
    const float* linb  = (const float*)d_in[5];
    const float* fcw   = (const float*)d_in[6];
    const float* fcb   = (const float*)d_in[7];
    float* out = (float*)d_out;

    float* ws   = (float*)d_ws;
    float* sig  = ws;                                   // 2048*1088
    float* psum = sig + (size_t)N_B * F_PAD;            // 16*1088
    float* psq  = psum + (size_t)SY * F_PAD;            // 16*1088
    float* Av   = psq + (size_t)SY * F_PAD;             // 1088
    float* Bv   = Av + F_PAD;                           // 1088
    float* tvec = Bv + F_PAD;                           // 1056
    float* part = tvec + F_SIG;                         // 8*104*1056
    float* opart = part;                                // alias: 2*2048*128 (part dead by k_out2)
    float* WfT  = part + (size_t)OSPLIT * KW_PAD * F_SIG;// 1056*128
    float* bfv  = WfT + (size_t)F_SIG * K_PAD;          // 128
    unsigned short* Ahi = (unsigned short*)(bfv + K_PAD);   // 36*512 ushort
    unsigned short* Alo = Ahi + 36 * 512;

    k_wt<<<72, 256, 0, stream>>>(convw, Ahi, Alo);
    k_convsig<<<N_B, 256, 0, stream>>>(feats, Ahi, Alo, sig);
    k_stats<<<dim3(5, SY), 256, 0, stream>>>(sig, psum, psq);
    k_ab<<<5, 256, 0, stream>>>(psum, psq, gamma, beta, Av, Bv);
    k_t<<<F_SIG, 256, 0, stream>>>(linw, Bv, linb, tvec);
    k_wf<<<dim3(5, 13, OSPLIT), 256, 0, stream>>>(fcw, linw, part);
    k_wfred<<<dim3(17, K_PAD), 64, 0, stream>>>(part, Av, WfT);
    k_bf<<<K_PAD, 256, 0, stream>>>(fcw, tvec, fcb, bfv);
    k_out2<<<512, 256, 0, stream>>>(sig, WfT, opart);
    k_osum<<<N_B * K_PAD / 256, 256, 0, stream>>>(opart, bfv, out);
}

// Round 7
// 131.416 us; speedup vs baseline: 1.0986x; 1.0986x over previous
//
#include <hip/hip_runtime.h>

#define N_B   2048
#define F_SIG 1056
#define F_PAD 1088
#define K_CLS 100
#define K_PAD 128
#define KW_PAD 104         // k rows allocated in part[] (13 y-blocks x 8)
#define DROW   52          // 49 real + 3 pad, 16B-aligned rows
#define OSPLIT  8
#define OCHUNK 132
#define XW     72          // ushorts per padded-position row (16B-mult, bank-spread)
#define SY     16          // k_stats partial row-groups
#define IHALF  528         // k_out i-split

typedef __attribute__((ext_vector_type(8))) short s8v;     // 8 bf16 in 4 VGPRs
typedef __attribute__((ext_vector_type(4))) float f4v;

__device__ __host__ __forceinline__ void split_bf16(float x, unsigned& h, unsigned& l) {
    unsigned u = __builtin_bit_cast(unsigned, x);
    unsigned hb = (u + 0x7FFFu + ((u >> 16) & 1u)) >> 16;
    float hf = __builtin_bit_cast(float, hb << 16);
    float r = x - hf;
    unsigned ur = __builtin_bit_cast(unsigned, r);
    unsigned lb = (ur + 0x7FFFu + ((ur >> 16) & 1u)) >> 16;
    h = hb & 0xFFFFu; l = lb & 0xFFFFu;
}

// ---------- prepack conv weights into MFMA A-fragments (hi/lo split) ----------
// frag f = ((tap*2+ch)*2+mt); element (lane,e): oc = mt*16+(lane&15),
// cin = ch*32+(lane>>4)*8+e, value = cw[oc][cin][tap]   (layout verified R4)
__global__ void k_wt(const float* __restrict__ cw, unsigned short* __restrict__ Ahi,
                     unsigned short* __restrict__ Alo) {
    int t = blockIdx.x * 256 + threadIdx.x;
    if (t >= 36 * 512) return;
    int f = t >> 9, r = t & 511, lane = r >> 3, e = r & 7;
    int mt = f & 1, ch = (f >> 1) & 1, tap = f >> 2;
    int oc  = mt * 16 + (lane & 15);
    int cin = ch * 32 + (lane >> 4) * 8 + e;
    float v = cw[oc * 576 + cin * 9 + tap];
    unsigned h, l;
    split_bf16(v, h, l);
    Ahi[t] = (unsigned short)h;
    Alo[t] = (unsigned short)l;
}

// ---------- MFMA conv(64->32,3x3,pad1) + Zhang signature depth-2, one image/block ----------
__launch_bounds__(256, 4)
__global__ void k_convsig(const float* __restrict__ x,
                          const unsigned short* __restrict__ Ahi,
                          const unsigned short* __restrict__ Alo,
                          float* __restrict__ sig) {
    __shared__ __align__(16) unsigned short xhi[100 * XW];   // [pad_pos][cin] hi-plane
    __shared__ __align__(16) unsigned short xlo[100 * XW];   // lo-plane
    __shared__ __align__(16) float ysT[64 * 36];             // [pos][oc] stride 36
    float* Ds   = (float*)xhi;          // 32*52   (x planes dead after conv)
    float* Cs   = Ds + 1664;            // 32*52   in-place -> strict 2D prefix P
    float* colS = Cs + 1664;            // 32*8    column sums for level-1
    const int tid = threadIdx.x;
    const int b = blockIdx.x;

    // --- stage: zero planes, then split/scatter feats (position-major) ---
    {
        unsigned* zh = (unsigned*)xhi;
        unsigned* zl = (unsigned*)xlo;
        for (int e = tid; e < 100 * XW / 2; e += 256) { zh[e] = 0u; zl[e] = 0u; }
    }
    __syncthreads();
    const float4* xb4 = reinterpret_cast<const float4*>(x + (size_t)b * 4096);
    for (int e = tid; e < 1024; e += 256) {
        float4 v = xb4[e];
        int cin = e >> 4, p = (e & 15) * 4;
        int ih = p >> 3, iw = p & 7;                   // iw in {0,4}
        int pp = (ih + 1) * 10 + (iw + 1);
        unsigned h, l;
        split_bf16(v.x, h, l); xhi[(pp+0)*XW + cin] = (unsigned short)h; xlo[(pp+0)*XW + cin] = (unsigned short)l;
        split_bf16(v.y, h, l); xhi[(pp+1)*XW + cin] = (unsigned short)h; xlo[(pp+1)*XW + cin] = (unsigned short)l;
        split_bf16(v.z, h, l); xhi[(pp+2)*XW + cin] = (unsigned short)h; xlo[(pp+2)*XW + cin] = (unsigned short)l;
        split_bf16(v.w, h, l); xhi[(pp+3)*XW + cin] = (unsigned short)h; xlo[(pp+3)*XW + cin] = (unsigned short)l;
    }
    __syncthreads();

    // --- MFMA conv: wave = one n-tile of 16 positions, 32 oc ---
    {
        const int wv = tid >> 6;
        const int lane = tid & 63;
        const int j16 = lane & 15, kg = lane >> 4;
        const int p2 = wv * 16 + j16;
        const int oh = p2 >> 3, ow = p2 & 7;
        const unsigned short* Hb = xhi + (oh * 10 + ow) * XW + kg * 8;
        const unsigned short* Lb = xlo + (oh * 10 + ow) * XW + kg * 8;
        const uint4* AH = reinterpret_cast<const uint4*>(Ahi) + lane;  // frag f at +f*64
        const uint4* AL = reinterpret_cast<const uint4*>(Alo) + lane;
        f4v acc0 = {0.f, 0.f, 0.f, 0.f};
        f4v acc1 = {0.f, 0.f, 0.f, 0.f};
#pragma unroll
        for (int k = 0; k < 18; ++k) {
            const int tap = k >> 1, ch = k & 1;
            const int th = tap / 3, tw = tap % 3;          // fold at compile time
            const int xoff = (th * 10 + tw) * XW + ch * 32;
            const int f0 = (tap * 2 + ch) * 2;
            uint4 bh = *reinterpret_cast<const uint4*>(Hb + xoff);
            uint4 bl = *reinterpret_cast<const uint4*>(Lb + xoff);
            uint4 a0h = AH[f0 * 64], a0l = AL[f0 * 64];
            uint4 a1h = AH[f0 * 64 + 64], a1l = AL[f0 * 64 + 64];
            s8v Bh = __builtin_bit_cast(s8v, bh);
            s8v Bl = __builtin_bit_cast(s8v, bl);
            s8v A0h = __builtin_bit_cast(s8v, a0h);
            s8v A0l = __builtin_bit_cast(s8v, a0l);
            s8v A1h = __builtin_bit_cast(s8v, a1h);
            s8v A1l = __builtin_bit_cast(s8v, a1l);
            acc0 = __builtin_amdgcn_mfma_f32_16x16x32_bf16(A0h, Bh, acc0, 0, 0, 0);
            acc0 = __builtin_amdgcn_mfma_f32_16x16x32_bf16(A0h, Bl, acc0, 0, 0, 0);
            acc0 = __builtin_amdgcn_mfma_f32_16x16x32_bf16(A0l, Bh, acc0, 0, 0, 0);
            acc1 = __builtin_amdgcn_mfma_f32_16x16x32_bf16(A1h, Bh, acc1, 0, 0, 0);
            acc1 = __builtin_amdgcn_mfma_f32_16x16x32_bf16(A1h, Bl, acc1, 0, 0, 0);
            acc1 = __builtin_amdgcn_mfma_f32_16x16x32_bf16(A1l, Bh, acc1, 0, 0, 0);
        }
        // C/D: col=lane&15 -> pos, row=(lane>>4)*4+reg -> oc
        *reinterpret_cast<f4v*>(ysT + p2 * 36 + kg * 4)      = acc0;
        *reinterpret_cast<f4v*>(ysT + p2 * 36 + 16 + kg * 4) = acc1;
    }
    __syncthreads();

    // --- fused D + strict column scan; thread = (c, j) ---
    if (tid < 224) {
        const int c = tid / 7, j = tid - (tid / 7) * 7;
        float a  = ysT[j * 36 + c];            // ys[0][j]
        float bq = ysT[(j + 1) * 36 + c];      // ys[0][j+1]
        float run = 0.f;
        float* Dc = Ds + c * DROW;
        float* Cc = Cs + c * DROW;
#pragma unroll
        for (int i = 0; i < 7; ++i) {
            float a2 = ysT[((i + 1) * 8 + j) * 36 + c];
            float b2 = ysT[((i + 1) * 8 + j + 1) * 36 + c];
            float d = (b2 - a2) - (bq - a);
            Dc[i * 7 + j] = d;
            Cc[i * 7 + j] = run;               // strict prefix along i
            run += d;
            a = a2; bq = b2;
        }
        colS[c * 8 + j] = run;                 // full column sum (for level-1)
    } else {
        const int c = tid - 224;               // zero D row pads
        Ds[c * DROW + 49] = 0.f; Ds[c * DROW + 50] = 0.f; Ds[c * DROW + 51] = 0.f;
    }
    __syncthreads();

    // --- in-place strict row scan: Cs becomes strict 2D prefix P; thread = (c, i) ---
    if (tid < 224) {
        const int c = tid / 7, i = tid - (tid / 7) * 7;
        float* Cc = Cs + c * DROW + i * 7;
        float run = 0.f;
#pragma unroll
        for (int j = 0; j < 7; ++j) {
            float v = Cc[j];
            Cc[j] = run;
            run += v;
        }
    } else {
        const int c = tid - 224;               // zero P row pads
        Cs[c * DROW + 49] = 0.f; Cs[c * DROW + 50] = 0.f; Cs[c * DROW + 51] = 0.f;
    }
    __syncthreads();

    // --- level-2: 2x2 register-blocked, vectorized LDS reads (P = Cs) ---
    {
        const int bc1 = tid >> 4, bc2 = tid & 15;
        const float* P0 = Cs + bc1 * DROW;
        const float* P1 = Cs + (bc1 + 16) * DROW;
        const float* D0 = Ds + bc2 * DROW;
        const float* D1 = Ds + (bc2 + 16) * DROW;
        float a00 = 0.f, a01 = 0.f, a10 = 0.f, a11 = 0.f;
#pragma unroll
        for (int qb = 0; qb < DROW; qb += 4) {
            float4 p0 = *reinterpret_cast<const float4*>(P0 + qb);
            float4 p1 = *reinterpret_cast<const float4*>(P1 + qb);
            float4 d0 = *reinterpret_cast<const float4*>(D0 + qb);
            float4 d1 = *reinterpret_cast<const float4*>(D1 + qb);
            a00 += p0.x*d0.x + p0.y*d0.y + p0.z*d0.z + p0.w*d0.w;
            a01 += p0.x*d1.x + p0.y*d1.y + p0.z*d1.z + p0.w*d1.w;
            a10 += p1.x*d0.x + p1.y*d0.y + p1.z*d0.z + p1.w*d0.w;
            a11 += p1.x*d1.x + p1.y*d1.y + p1.z*d1.z + p1.w*d1.w;
        }
        float* so = sig + (size_t)b * F_PAD + 32;
        so[bc1 * 32 + bc2]               = a00;
        so[bc1 * 32 + (bc2 + 16)]        = a01;
        so[(bc1 + 16) * 32 + bc2]        = a10;
        so[(bc1 + 16) * 32 + (bc2 + 16)] = a11;
    }

    // --- level-1 from column sums + zero sig pad ---
    if (tid < 32) {
        const float* cr = colS + tid * 8;
        float s = cr[0] + cr[1] + cr[2] + cr[3] + cr[4] + cr[5] + cr[6];
        sig[(size_t)b * F_PAD + tid] = s;
    } else if (tid < 64) {
        sig[(size_t)b * F_PAD + F_SIG + (tid - 32)] = 0.f;
    }
}

// ---------- per-feature partial sum / sumsq (no atomics, no init, 4-row ILP) ----------
__global__ void k_stats(const float* __restrict__ sig, float* __restrict__ psum,
                        float* __restrict__ psq) {
    int f = blockIdx.x * 256 + threadIdx.x;
    if (f >= F_SIG) return;
    int y = blockIdx.y;
    const float* sp = sig + (size_t)(y * 128) * F_PAD + f;
    float s = 0.f, q = 0.f;
    for (int r = 0; r < 128; r += 4) {
        float v0 = sp[(size_t)(r + 0) * F_PAD];
        float v1 = sp[(size_t)(r + 1) * F_PAD];
        float v2 = sp[(size_t)(r + 2) * F_PAD];
        float v3 = sp[(size_t)(r + 3) * F_PAD];
        s += v0 + v1 + v2 + v3;
        q = fmaf(v0, v0, q); q = fmaf(v1, v1, q);
        q = fmaf(v2, v2, q); q = fmaf(v3, v3, q);
    }
    psum[(size_t)y * F_PAD + f] = s;
    psq[(size_t)y * F_PAD + f]  = q;
}

// ---------- BN fold (reduces the 16 partials) ----------
__global__ void k_ab(const float* __restrict__ psum, const float* __restrict__ psq,
                     const float* __restrict__ gamma, const float* __restrict__ beta,
                     float* __restrict__ Av, float* __restrict__ Bv) {
    int i = blockIdx.x * 256 + threadIdx.x;
    if (i >= F_PAD) return;
    float a = 0.f, bb = 0.f;
    if (i < F_SIG) {
        float s = 0.f, q = 0.f;
#pragma unroll
        for (int z = 0; z < SY; ++z) {
            s += psum[(size_t)z * F_PAD + i];
            q += psq[(size_t)z * F_PAD + i];
        }
        float m   = s * (1.f / 2048.f);
        float var = q * (1.f / 2048.f) - m * m;
        a  = gamma[i] / sqrtf(var + 1e-5f);
        bb = beta[i] - m * a;
    }
    Av[i] = a;
    Bv[i] = bb;
}

// ---------- t[o] = lin_b[o] + sum_i Bv[i]*lin_w[o,i] ----------
__global__ void k_t(const float* __restrict__ lw, const float* __restrict__ Bv,
                    const float* __restrict__ lb, float* __restrict__ tvec) {
    int o = blockIdx.x, tid = threadIdx.x;
    const float* lr = lw + (size_t)o * F_SIG;
    float s = 0.f;
    for (int i = tid; i < F_SIG; i += 256) s = fmaf(Bv[i], lr[i], s);
#pragma unroll
    for (int d = 32; d; d >>= 1) s += __shfl_xor(s, d);
    __shared__ float red[4];
    if ((tid & 63) == 0) red[tid >> 6] = s;
    __syncthreads();
    if (tid == 0) tvec[o] = lb[o] + red[0] + red[1] + red[2] + red[3];
}

// ---------- split-K partials: part[z][k][i] += fcw[k,o]*lin_w[o,i], 8 k per block ----------
__launch_bounds__(256)
__global__ void k_wf(const float* __restrict__ fcw, const float* __restrict__ lw,
                     float* __restrict__ part) {
    const int wv = threadIdx.x >> 6;
    const int k0 = blockIdx.y * 8 + wv * 2;         // this wave's two k rows
    const int z  = blockIdx.z;
    const int ib = blockIdx.x * 256 + (threadIdx.x & 63) * 4;
    if (ib >= F_SIG) return;
    const float* f0 = fcw + (size_t)min(k0,     K_CLS - 1) * F_SIG;
    const float* f1 = fcw + (size_t)min(k0 + 1, K_CLS - 1) * F_SIG;
    const int o0 = z * OCHUNK;
    float4 A0 = {0.f,0.f,0.f,0.f}, A1 = {0.f,0.f,0.f,0.f};
    for (int o = o0; o < o0 + OCHUNK; ++o) {
        float s0 = f0[o], s1 = f1[o];
        float4 v = *reinterpret_cast<const float4*>(lw + (size_t)o * F_SIG + ib);
        A0.x = fmaf(s0, v.x, A0.x); A0.y = fmaf(s0, v.y, A0.y);
        A0.z = fmaf(s0, v.z, A0.z); A0.w = fmaf(s0, v.w, A0.w);
        A1.x = fmaf(s1, v.x, A1.x); A1.y = fmaf(s1, v.y, A1.y);
        A1.z = fmaf(s1, v.z, A1.z); A1.w = fmaf(s1, v.w, A1.w);
    }
    *reinterpret_cast<float4*>(part + ((size_t)z * KW_PAD + k0) * F_SIG + ib)     = A0;
    *reinterpret_cast<float4*>(part + ((size_t)z * KW_PAD + k0 + 1) * F_SIG + ib) = A1;
}

// ---------- reduce partials, fold Av, emit WfT[i*128 + k] ----------
__launch_bounds__(64)
__global__ void k_wfred(const float* __restrict__ part, const float* __restrict__ Av,
                        float* __restrict__ WfT) {
    const int i = blockIdx.x * 64 + threadIdx.x;
    const int k = blockIdx.y;
    if (i >= F_SIG) return;
    float w = 0.f;
    if (k < K_CLS) {
        float s = 0.f;
#pragma unroll
        for (int z = 0; z < OSPLIT; ++z)
            s += part[((size_t)z * KW_PAD + k) * F_SIG + i];
        w = Av[i] * s;
    }
    WfT[(size_t)i * K_PAD + k] = w;
}

// ---------- bf[k] = fc_b[k] + sum_o fc_w[k,o]*t[o] ----------
__global__ void k_bf(const float* __restrict__ fcw, const float* __restrict__ tvec,
                     const float* __restrict__ fcb, float* __restrict__ bf) {
    int k = blockIdx.x, tid = threadIdx.x;
    float s = 0.f;
    if (k < K_CLS) {
        const float* fr = fcw + (size_t)k * F_SIG;
        for (int o = tid; o < F_SIG; o += 256) s = fmaf(fr[o], tvec[o], s);
    }
#pragma unroll
    for (int d = 32; d; d >>= 1) s += __shfl_xor(s, d);
    __shared__ float red[4];
    if ((tid & 63) == 0) red[tid >> 6] = s;
    __syncthreads();
    if (tid == 0) {
        float tot = red[0] + red[1] + red[2] + red[3];
        bf[k] = (k < K_CLS) ? (tot + fcb[k]) : 0.f;
    }
}

#define OUT_FMA4(sv, wv_) do { \
    acc.x = fmaf((sv), (wv_).x, acc.x); \
    acc.y = fmaf((sv), (wv_).y, acc.y); \
    acc.z = fmaf((sv), (wv_).z, acc.z); \
    acc.w = fmaf((sv), (wv_).w, acc.w); } while (0)

// ---------- opart[z][r][k] = sum_{i in half z} sig[r,i]*WfT[i,k]; 8-deep load ILP ----------
__launch_bounds__(256)
__global__ void k_out2(const float* __restrict__ sig, const float* __restrict__ WfT,
                       float* __restrict__ opart) {
    __shared__ __align__(16) float sl[8 * IHALF];
    const int tid = threadIdx.x;
    const int z  = blockIdx.x & 1;
    const int r0 = (blockIdx.x >> 1) * 8;
    const int i0 = z * IHALF;
    for (int e = tid; e < 8 * (IHALF / 4); e += 256) {
        int row = e / (IHALF / 4), c4 = e - row * (IHALF / 4);
        float4 v = *reinterpret_cast<const float4*>(sig + (size_t)(r0 + row) * F_PAD + i0 + c4 * 4);
        *reinterpret_cast<float4*>(sl + row * IHALF + c4 * 4) = v;
    }
    __syncthreads();

    const int rl = tid >> 5;          // 0..7
    const int kb = tid & 31;
    const float4* W4 = reinterpret_cast<const float4*>(WfT) + (size_t)i0 * 32 + kb;
    const float4* s4 = reinterpret_cast<const float4*>(sl + rl * IHALF);
    float4 acc = {0.f, 0.f, 0.f, 0.f};
    for (int g = 0; g < IHALF / 8; ++g) {
        // issue all 8 W loads + 2 LDS reads before consuming -> 8-deep vmcnt pipeline
        float4 w0 = W4[(g * 8 + 0) * 32];
        float4 w1 = W4[(g * 8 + 1) * 32];
        float4 w2 = W4[(g * 8 + 2) * 32];
        float4 w3 = W4[(g * 8 + 3) * 32];
        float4 w4 = W4[(g * 8 + 4) * 32];
        float4 w5 = W4[(g * 8 + 5) * 32];
        float4 w6 = W4[(g * 8 + 6) * 32];
        float4 w7 = W4[(g * 8 + 7) * 32];
        float4 sa = s4[g * 2], sb = s4[g * 2 + 1];
        OUT_FMA4(sa.x, w0); OUT_FMA4(sa.y, w1);
        OUT_FMA4(sa.z, w2); OUT_FMA4(sa.w, w3);
        OUT_FMA4(sb.x, w4); OUT_FMA4(sb.y, w5);
        OUT_FMA4(sb.z, w6); OUT_FMA4(sb.w, w7);
    }
    float4* op = reinterpret_cast<float4*>(opart);
    op[((size_t)z * N_B + r0 + rl) * 32 + kb] = acc;
}

// ---------- out[r,k] = opart[0][r][k] + opart[1][r][k] + bf[k] ----------
__launch_bounds__(256)
__global__ void k_osum(const float* __restrict__ opart, const float* __restrict__ bf,
                       float* __restrict__ out) {
    int t = blockIdx.x * 256 + threadIdx.x;
    int r = t >> 7, k = t & 127;
    if (k < K_CLS)
        out[(size_t)r * K_CLS + k] =
            opart[(size_t)r * K_PAD + k] + opart[(size_t)(N_B + r) * K_PAD + k] + bf[k];
}

extern "C" void kernel_launch(void* const* d_in, const int* in_sizes, int n_in,
                              void* d_out, int out_size, void* d_ws, size_t ws_size,
                              hipStream_t stream) {
    (void)in_sizes; (void)n_in; (void)out_size; (void)ws_size;
    const float* feats = (const float*)d_in[0];
    const float* convw = (const float*)d_in[1];
    const float* gamma = (const float*)d_in[2];
    const float* beta  = (const float*)d_in[3];
    const float* linw  = (const float*)d_in[4];
    const float* linb  = (const float*)d_in[5];
    const float* fcw   = (const float*)d_in[6];
    const float* fcb   = (const float*)d_in[7];
    float* out = (float*)d_out;

    float* ws   = (float*)d_ws;
    float* sig  = ws;                                   // 2048*1088
    float* psum = sig + (size_t)N_B * F_PAD;            // 16*1088
    float* psq  = psum + (size_t)SY * F_PAD;            // 16*1088
    float* Av   = psq + (size_t)SY * F_PAD;             // 1088
    float* Bv   = Av + F_PAD;                           // 1088
    float* tvec = Bv + F_PAD;                           // 1056
    float* part = tvec + F_SIG;                         // 8*104*1056
    float* opart = part;                                // alias: 2*2048*128 (part dead by k_out2)
    float* WfT  = part + (size_t)OSPLIT * KW_PAD * F_SIG;// 1056*128
    float* bfv  = WfT + (size_t)F_SIG * K_PAD;          // 128
    unsigned short* Ahi = (unsigned short*)(bfv + K_PAD);   // 36*512 ushort
    unsigned short* Alo = Ahi + 36 * 512;

    k_wt<<<72, 256, 0, stream>>>(convw, Ahi, Alo);
    k_convsig<<<N_B, 256, 0, stream>>>(feats, Ahi, Alo, sig);
    k_stats<<<dim3(5, SY), 256, 0, stream>>>(sig, psum, psq);
    k_ab<<<5, 256, 0, stream>>>(psum, psq, gamma, beta, Av, Bv);
    k_t<<<F_SIG, 256, 0, stream>>>(linw, Bv, linb, tvec);
    k_wf<<<dim3(5, 13, OSPLIT), 256, 0, stream>>>(fcw, linw, part);
    k_wfred<<<dim3(17, K_PAD), 64, 0, stream>>>(part, Av, WfT);
    k_bf<<<K_PAD, 256, 0, stream>>>(fcw, tvec, fcb, bfv);
    k_out2<<<512, 256, 0, stream>>>(sig, WfT, opart);
    k_osum<<<N_B * K_PAD / 256, 256, 0, stream>>>(opart, bfv, out);
}

// Round 8
// 117.693 us; speedup vs baseline: 1.2267x; 1.1166x over previous
//
#include <hip/hip_runtime.h>

#define N_B   2048
#define F_SIG 1056
#define F_PAD 1088
#define K_CLS 100
#define K_PAD 128
#define KW_PAD 112         // k rows allocated in part[] (7 y-blocks x 16)
#define DROW   52          // 49 real + 3 pad, 16B-aligned rows
#define OSPLIT  8
#define OCHUNK 132
#define XW     72          // ushorts per padded-position row (16B-mult, bank-spread)
#define SY     32          // k_stats partial row-groups

typedef __attribute__((ext_vector_type(8))) short s8v;     // 8 bf16 in 4 VGPRs
typedef __attribute__((ext_vector_type(4))) float f4v;

__device__ __host__ __forceinline__ void split_bf16(float x, unsigned& h, unsigned& l) {
    unsigned u = __builtin_bit_cast(unsigned, x);
    unsigned hb = (u + 0x7FFFu + ((u >> 16) & 1u)) >> 16;
    float hf = __builtin_bit_cast(float, hb << 16);
    float r = x - hf;
    unsigned ur = __builtin_bit_cast(unsigned, r);
    unsigned lb = (ur + 0x7FFFu + ((ur >> 16) & 1u)) >> 16;
    h = hb & 0xFFFFu; l = lb & 0xFFFFu;
}

// ---------- prepack conv weights into MFMA A-fragments (hi/lo split) ----------
// frag f = ((tap*2+ch)*2+mt); element (lane,e): oc = mt*16+(lane&15),
// cin = ch*32+(lane>>4)*8+e, value = cw[oc][cin][tap]   (layout verified R4)
__global__ void k_wt(const float* __restrict__ cw, unsigned short* __restrict__ Ahi,
                     unsigned short* __restrict__ Alo) {
    int t = blockIdx.x * 256 + threadIdx.x;
    if (t >= 36 * 512) return;
    int f = t >> 9, r = t & 511, lane = r >> 3, e = r & 7;
    int mt = f & 1, ch = (f >> 1) & 1, tap = f >> 2;
    int oc  = mt * 16 + (lane & 15);
    int cin = ch * 32 + (lane >> 4) * 8 + e;
    float v = cw[oc * 576 + cin * 9 + tap];
    unsigned h, l;
    split_bf16(v, h, l);
    Ahi[t] = (unsigned short)h;
    Alo[t] = (unsigned short)l;
}

// ---------- MFMA conv(64->32,3x3,pad1) + Zhang signature depth-2, one image/block ----------
__launch_bounds__(256, 4)
__global__ void k_convsig(const float* __restrict__ x,
                          const unsigned short* __restrict__ Ahi,
                          const unsigned short* __restrict__ Alo,
                          float* __restrict__ sig) {
    __shared__ __align__(16) unsigned short xhi[100 * XW];   // [pad_pos][cin] hi-plane
    __shared__ __align__(16) unsigned short xlo[100 * XW];   // lo-plane
    __shared__ __align__(16) float ysT[64 * 36];             // [pos][oc] stride 36
    float* Ds   = (float*)xhi;          // 32*52   (x planes dead after conv)
    float* Cs   = Ds + 1664;            // 32*52   in-place -> strict 2D prefix P
    float* colS = Cs + 1664;            // 32*8    column sums for level-1
    const int tid = threadIdx.x;
    const int b = blockIdx.x;

    // --- stage: zero planes, then split/scatter feats (position-major) ---
    {
        unsigned* zh = (unsigned*)xhi;
        unsigned* zl = (unsigned*)xlo;
        for (int e = tid; e < 100 * XW / 2; e += 256) { zh[e] = 0u; zl[e] = 0u; }
    }
    __syncthreads();
    const float4* xb4 = reinterpret_cast<const float4*>(x + (size_t)b * 4096);
    {
        float4 v0 = xb4[tid], v1 = xb4[tid + 256], v2 = xb4[tid + 512], v3 = xb4[tid + 768];
#pragma unroll
        for (int u = 0; u < 4; ++u) {
            float4 v = (u == 0) ? v0 : (u == 1) ? v1 : (u == 2) ? v2 : v3;
            int e = tid + u * 256;
            int cin = e >> 4, p = (e & 15) * 4;
            int ih = p >> 3, iw = p & 7;                   // iw in {0,4}
            int pp = (ih + 1) * 10 + (iw + 1);
            unsigned h, l;
            split_bf16(v.x, h, l); xhi[(pp+0)*XW + cin] = (unsigned short)h; xlo[(pp+0)*XW + cin] = (unsigned short)l;
            split_bf16(v.y, h, l); xhi[(pp+1)*XW + cin] = (unsigned short)h; xlo[(pp+1)*XW + cin] = (unsigned short)l;
            split_bf16(v.z, h, l); xhi[(pp+2)*XW + cin] = (unsigned short)h; xlo[(pp+2)*XW + cin] = (unsigned short)l;
            split_bf16(v.w, h, l); xhi[(pp+3)*XW + cin] = (unsigned short)h; xlo[(pp+3)*XW + cin] = (unsigned short)l;
        }
    }
    __syncthreads();

    // --- MFMA conv: wave = one n-tile of 16 positions, 32 oc; A double-buffered ---
    {
        const int wv = tid >> 6;
        const int lane = tid & 63;
        const int j16 = lane & 15, kg = lane >> 4;
        const int p2 = wv * 16 + j16;
        const int oh = p2 >> 3, ow = p2 & 7;
        const unsigned short* Hb = xhi + (oh * 10 + ow) * XW + kg * 8;
        const unsigned short* Lb = xlo + (oh * 10 + ow) * XW + kg * 8;
        const uint4* AH = reinterpret_cast<const uint4*>(Ahi) + lane;  // frag f at +f*64
        const uint4* AL = reinterpret_cast<const uint4*>(Alo) + lane;
        f4v acc0 = {0.f, 0.f, 0.f, 0.f};
        f4v acc1 = {0.f, 0.f, 0.f, 0.f};
        uint4 a0h = AH[0], a0l = AL[0], a1h = AH[64], a1l = AL[64];
#pragma unroll
        for (int k = 0; k < 18; ++k) {
            const int tap = k >> 1, ch = k & 1;
            const int th = tap / 3, tw = tap % 3;          // fold at compile time
            const int xoff = (th * 10 + tw) * XW + ch * 32;
            uint4 bh = *reinterpret_cast<const uint4*>(Hb + xoff);
            uint4 bl = *reinterpret_cast<const uint4*>(Lb + xoff);
            uint4 n0h, n0l, n1h, n1l;
            if (k < 17) {
                const int kn = k + 1;
                const int fn = ((kn >> 1) * 2 + (kn & 1)) * 2;
                n0h = AH[fn * 64];      n0l = AL[fn * 64];
                n1h = AH[fn * 64 + 64]; n1l = AL[fn * 64 + 64];
            }
            s8v Bh = __builtin_bit_cast(s8v, bh);
            s8v Bl = __builtin_bit_cast(s8v, bl);
            s8v A0h = __builtin_bit_cast(s8v, a0h);
            s8v A0l = __builtin_bit_cast(s8v, a0l);
            s8v A1h = __builtin_bit_cast(s8v, a1h);
            s8v A1l = __builtin_bit_cast(s8v, a1l);
            acc0 = __builtin_amdgcn_mfma_f32_16x16x32_bf16(A0h, Bh, acc0, 0, 0, 0);
            acc0 = __builtin_amdgcn_mfma_f32_16x16x32_bf16(A0h, Bl, acc0, 0, 0, 0);
            acc0 = __builtin_amdgcn_mfma_f32_16x16x32_bf16(A0l, Bh, acc0, 0, 0, 0);
            acc1 = __builtin_amdgcn_mfma_f32_16x16x32_bf16(A1h, Bh, acc1, 0, 0, 0);
            acc1 = __builtin_amdgcn_mfma_f32_16x16x32_bf16(A1h, Bl, acc1, 0, 0, 0);
            acc1 = __builtin_amdgcn_mfma_f32_16x16x32_bf16(A1l, Bh, acc1, 0, 0, 0);
            if (k < 17) { a0h = n0h; a0l = n0l; a1h = n1h; a1l = n1l; }
        }
        // C/D: col=lane&15 -> pos, row=(lane>>4)*4+reg -> oc
        *reinterpret_cast<f4v*>(ysT + p2 * 36 + kg * 4)      = acc0;
        *reinterpret_cast<f4v*>(ysT + p2 * 36 + 16 + kg * 4) = acc1;
    }
    __syncthreads();

    // --- fused D + strict column scan; thread = (c, j) ---
    if (tid < 224) {
        const int c = tid / 7, j = tid - (tid / 7) * 7;
        float a  = ysT[j * 36 + c];            // ys[0][j]
        float bq = ysT[(j + 1) * 36 + c];      // ys[0][j+1]
        float run = 0.f;
        float* Dc = Ds + c * DROW;
        float* Cc = Cs + c * DROW;
#pragma unroll
        for (int i = 0; i < 7; ++i) {
            float a2 = ysT[((i + 1) * 8 + j) * 36 + c];
            float b2 = ysT[((i + 1) * 8 + j + 1) * 36 + c];
            float d = (b2 - a2) - (bq - a);
            Dc[i * 7 + j] = d;
            Cc[i * 7 + j] = run;               // strict prefix along i
            run += d;
            a = a2; bq = b2;
        }
        colS[c * 8 + j] = run;                 // full column sum (for level-1)
    } else {
        const int c = tid - 224;               // zero D row pads
        Ds[c * DROW + 49] = 0.f; Ds[c * DROW + 50] = 0.f; Ds[c * DROW + 51] = 0.f;
    }
    __syncthreads();

    // --- in-place strict row scan: Cs becomes strict 2D prefix P; thread = (c, i) ---
    if (tid < 224) {
        const int c = tid / 7, i = tid - (tid / 7) * 7;
        float* Cc = Cs + c * DROW + i * 7;
        float run = 0.f;
#pragma unroll
        for (int j = 0; j < 7; ++j) {
            float v = Cc[j];
            Cc[j] = run;
            run += v;
        }
    } else {
        const int c = tid - 224;               // zero P row pads
        Cs[c * DROW + 49] = 0.f; Cs[c * DROW + 50] = 0.f; Cs[c * DROW + 51] = 0.f;
    }
    __syncthreads();

    // --- level-2: 2x2 register-blocked, vectorized LDS reads (P = Cs) ---
    {
        const int bc1 = tid >> 4, bc2 = tid & 15;
        const float* P0 = Cs + bc1 * DROW;
        const float* P1 = Cs + (bc1 + 16) * DROW;
        const float* D0 = Ds + bc2 * DROW;
        const float* D1 = Ds + (bc2 + 16) * DROW;
        float a00 = 0.f, a01 = 0.f, a10 = 0.f, a11 = 0.f;
#pragma unroll
        for (int qb = 0; qb < DROW; qb += 4) {
            float4 p0 = *reinterpret_cast<const float4*>(P0 + qb);
            float4 p1 = *reinterpret_cast<const float4*>(P1 + qb);
            float4 d0 = *reinterpret_cast<const float4*>(D0 + qb);
            float4 d1 = *reinterpret_cast<const float4*>(D1 + qb);
            a00 += p0.x*d0.x + p0.y*d0.y + p0.z*d0.z + p0.w*d0.w;
            a01 += p0.x*d1.x + p0.y*d1.y + p0.z*d1.z + p0.w*d1.w;
            a10 += p1.x*d0.x + p1.y*d0.y + p1.z*d0.z + p1.w*d0.w;
            a11 += p1.x*d1.x + p1.y*d1.y + p1.z*d1.z + p1.w*d1.w;
        }
        float* so = sig + (size_t)b * F_PAD + 32;
        so[bc1 * 32 + bc2]               = a00;
        so[bc1 * 32 + (bc2 + 16)]        = a01;
        so[(bc1 + 16) * 32 + bc2]        = a10;
        so[(bc1 + 16) * 32 + (bc2 + 16)] = a11;
    }

    // --- level-1 from column sums + zero sig pad ---
    if (tid < 32) {
        const float* cr = colS + tid * 8;
        float s = cr[0] + cr[1] + cr[2] + cr[3] + cr[4] + cr[5] + cr[6];
        sig[(size_t)b * F_PAD + tid] = s;
    } else if (tid < 64) {
        sig[(size_t)b * F_PAD + F_SIG + (tid - 32)] = 0.f;
    }
}

// ---------- per-feature partial sum / sumsq (no atomics, no init, 4-row ILP) ----------
__global__ void k_stats(const float* __restrict__ sig, float* __restrict__ psum,
                        float* __restrict__ psq) {
    int f = blockIdx.x * 256 + threadIdx.x;
    if (f >= F_SIG) return;
    int y = blockIdx.y;
    const float* sp = sig + (size_t)(y * 64) * F_PAD + f;
    float s = 0.f, q = 0.f;
    for (int r = 0; r < 64; r += 4) {
        float v0 = sp[(size_t)(r + 0) * F_PAD];
        float v1 = sp[(size_t)(r + 1) * F_PAD];
        float v2 = sp[(size_t)(r + 2) * F_PAD];
        float v3 = sp[(size_t)(r + 3) * F_PAD];
        s += v0 + v1 + v2 + v3;
        q = fmaf(v0, v0, q); q = fmaf(v1, v1, q);
        q = fmaf(v2, v2, q); q = fmaf(v3, v3, q);
    }
    psum[(size_t)y * F_PAD + f] = s;
    psq[(size_t)y * F_PAD + f]  = q;
}

// ---------- BN fold (reduces the 32 partials) ----------
__global__ void k_ab(const float* __restrict__ psum, const float* __restrict__ psq,
                     const float* __restrict__ gamma, const float* __restrict__ beta,
                     float* __restrict__ Av, float* __restrict__ Bv) {
    int i = blockIdx.x * 256 + threadIdx.x;
    if (i >= F_PAD) return;
    float a = 0.f, bb = 0.f;
    if (i < F_SIG) {
        float s = 0.f, q = 0.f;
#pragma unroll
        for (int z = 0; z < SY; ++z) {
            s += psum[(size_t)z * F_PAD + i];
            q += psq[(size_t)z * F_PAD + i];
        }
        float m   = s * (1.f / 2048.f);
        float var = q * (1.f / 2048.f) - m * m;
        a  = gamma[i] / sqrtf(var + 1e-5f);
        bb = beta[i] - m * a;
    }
    Av[i] = a;
    Bv[i] = bb;
}

// ---------- t[o] = lin_b[o] + sum_i Bv[i]*lin_w[o,i] ----------
__global__ void k_t(const float* __restrict__ lw, const float* __restrict__ Bv,
                    const float* __restrict__ lb, float* __restrict__ tvec) {
    int o = blockIdx.x, tid = threadIdx.x;
    const float* lr = lw + (size_t)o * F_SIG;
    float s = 0.f;
    for (int i = tid; i < F_SIG; i += 256) s = fmaf(Bv[i], lr[i], s);
#pragma unroll
    for (int d = 32; d; d >>= 1) s += __shfl_xor(s, d);
    __shared__ float red[4];
    if ((tid & 63) == 0) red[tid >> 6] = s;
    __syncthreads();
    if (tid == 0) tvec[o] = lb[o] + red[0] + red[1] + red[2] + red[3];
}

// ---------- split-K partials: part[z][k][i] = sum_{o in chunk z} fcw[k,o]*lin_w[o,i]; 16 k/block ----------
__launch_bounds__(256)
__global__ void k_wf(const float* __restrict__ fcw, const float* __restrict__ lw,
                     float* __restrict__ part) {
    const int wv = threadIdx.x >> 6;
    const int k0 = blockIdx.y * 16 + wv * 4;        // this wave's four k rows
    const int z  = blockIdx.z;
    const int ib = blockIdx.x * 256 + (threadIdx.x & 63) * 4;
    if (ib >= F_SIG) return;
    const float* f0 = fcw + (size_t)min(k0,     K_CLS - 1) * F_SIG;
    const float* f1 = fcw + (size_t)min(k0 + 1, K_CLS - 1) * F_SIG;
    const float* f2 = fcw + (size_t)min(k0 + 2, K_CLS - 1) * F_SIG;
    const float* f3 = fcw + (size_t)min(k0 + 3, K_CLS - 1) * F_SIG;
    const int o0 = z * OCHUNK;
    float4 A0 = {0.f,0.f,0.f,0.f}, A1 = {0.f,0.f,0.f,0.f};
    float4 A2 = {0.f,0.f,0.f,0.f}, A3 = {0.f,0.f,0.f,0.f};
    for (int o = o0; o < o0 + OCHUNK; ++o) {
        float4 v = *reinterpret_cast<const float4*>(lw + (size_t)o * F_SIG + ib);
        float s0 = f0[o], s1 = f1[o], s2 = f2[o], s3 = f3[o];
        A0.x = fmaf(s0, v.x, A0.x); A0.y = fmaf(s0, v.y, A0.y);
        A0.z = fmaf(s0, v.z, A0.z); A0.w = fmaf(s0, v.w, A0.w);
        A1.x = fmaf(s1, v.x, A1.x); A1.y = fmaf(s1, v.y, A1.y);
        A1.z = fmaf(s1, v.z, A1.z); A1.w = fmaf(s1, v.w, A1.w);
        A2.x = fmaf(s2, v.x, A2.x); A2.y = fmaf(s2, v.y, A2.y);
        A2.z = fmaf(s2, v.z, A2.z); A2.w = fmaf(s2, v.w, A2.w);
        A3.x = fmaf(s3, v.x, A3.x); A3.y = fmaf(s3, v.y, A3.y);
        A3.z = fmaf(s3, v.z, A3.z); A3.w = fmaf(s3, v.w, A3.w);
    }
    *reinterpret_cast<float4*>(part + ((size_t)z * KW_PAD + k0 + 0) * F_SIG + ib) = A0;
    *reinterpret_cast<float4*>(part + ((size_t)z * KW_PAD + k0 + 1) * F_SIG + ib) = A1;
    *reinterpret_cast<float4*>(part + ((size_t)z * KW_PAD + k0 + 2) * F_SIG + ib) = A2;
    *reinterpret_cast<float4*>(part + ((size_t)z * KW_PAD + k0 + 3) * F_SIG + ib) = A3;
}

// ---------- reduce partials, fold Av, emit WfT[i*128 + k] ----------
__launch_bounds__(64)
__global__ void k_wfred(const float* __restrict__ part, const float* __restrict__ Av,
                        float* __restrict__ WfT) {
    const int i = blockIdx.x * 64 + threadIdx.x;
    const int k = blockIdx.y;
    if (i >= F_SIG) return;
    float w = 0.f;
    if (k < K_CLS) {
        float s = 0.f;
#pragma unroll
        for (int z = 0; z < OSPLIT; ++z)
            s += part[((size_t)z * KW_PAD + k) * F_SIG + i];
        w = Av[i] * s;
    }
    WfT[(size_t)i * K_PAD + k] = w;
}

// ---------- bf[k] = fc_b[k] + sum_o fc_w[k,o]*t[o] ----------
__global__ void k_bf(const float* __restrict__ fcw, const float* __restrict__ tvec,
                     const float* __restrict__ fcb, float* __restrict__ bf) {
    int k = blockIdx.x, tid = threadIdx.x;
    float s = 0.f;
    if (k < K_CLS) {
        const float* fr = fcw + (size_t)k * F_SIG;
        for (int o = tid; o < F_SIG; o += 256) s = fmaf(fr[o], tvec[o], s);
    }
#pragma unroll
    for (int d = 32; d; d >>= 1) s += __shfl_xor(s, d);
    __shared__ float red[4];
    if ((tid & 63) == 0) red[tid >> 6] = s;
    __syncthreads();
    if (tid == 0) {
        float tot = red[0] + red[1] + red[2] + red[3];
        bf[k] = (k < K_CLS) ? (tot + fcb[k]) : 0.f;
    }
}

// ---------- out[r,k]: 8 rows/block, waves split i-range, W read once per block ----------
__launch_bounds__(256)
__global__ void k_out3(const float* __restrict__ sig, const float* __restrict__ WfT,
                       const float* __restrict__ bf, float* __restrict__ out) {
    __shared__ __align__(16) float slT[F_SIG * 8];   // [i][row] 33.8 KB
    __shared__ __align__(16) float red[4 * 8 * K_PAD]; // 16 KB
    const int tid = threadIdx.x;
    const int r0 = blockIdx.x * 8;
    // stage 8 sig rows transposed: slT[i][row]
    for (int e = tid; e < 8 * (F_SIG / 4); e += 256) {
        int row = e & 7, c4 = e >> 3;
        float4 v = *reinterpret_cast<const float4*>(sig + (size_t)(r0 + row) * F_PAD + c4 * 4);
        slT[(c4 * 4 + 0) * 8 + row] = v.x;
        slT[(c4 * 4 + 1) * 8 + row] = v.y;
        slT[(c4 * 4 + 2) * 8 + row] = v.z;
        slT[(c4 * 4 + 3) * 8 + row] = v.w;
    }
    __syncthreads();

    const int wv = tid >> 6, lane = tid & 63;
    const int i0 = wv * 264;
    const float2* Wp = reinterpret_cast<const float2*>(WfT) + lane;  // row i at +i*64
    float2 acc[8];
#pragma unroll
    for (int r = 0; r < 8; ++r) acc[r] = make_float2(0.f, 0.f);
    for (int g = 0; g < 33; ++g) {
        const int ib = i0 + g * 8;
        float2 w0 = Wp[(size_t)(ib + 0) * 64];
        float2 w1 = Wp[(size_t)(ib + 1) * 64];
        float2 w2 = Wp[(size_t)(ib + 2) * 64];
        float2 w3 = Wp[(size_t)(ib + 3) * 64];
        float2 w4 = Wp[(size_t)(ib + 4) * 64];
        float2 w5 = Wp[(size_t)(ib + 5) * 64];
        float2 w6 = Wp[(size_t)(ib + 6) * 64];
        float2 w7 = Wp[(size_t)(ib + 7) * 64];
#pragma unroll
        for (int j = 0; j < 8; ++j) {
            float2 wj = (j == 0) ? w0 : (j == 1) ? w1 : (j == 2) ? w2 : (j == 3) ? w3
                      : (j == 4) ? w4 : (j == 5) ? w5 : (j == 6) ? w6 : w7;
            const float4* sp = reinterpret_cast<const float4*>(slT + (ib + j) * 8);
            float4 ra = sp[0], rb = sp[1];
            acc[0].x = fmaf(ra.x, wj.x, acc[0].x); acc[0].y = fmaf(ra.x, wj.y, acc[0].y);
            acc[1].x = fmaf(ra.y, wj.x, acc[1].x); acc[1].y = fmaf(ra.y, wj.y, acc[1].y);
            acc[2].x = fmaf(ra.z, wj.x, acc[2].x); acc[2].y = fmaf(ra.z, wj.y, acc[2].y);
            acc[3].x = fmaf(ra.w, wj.x, acc[3].x); acc[3].y = fmaf(ra.w, wj.y, acc[3].y);
            acc[4].x = fmaf(rb.x, wj.x, acc[4].x); acc[4].y = fmaf(rb.x, wj.y, acc[4].y);
            acc[5].x = fmaf(rb.y, wj.x, acc[5].x); acc[5].y = fmaf(rb.y, wj.y, acc[5].y);
            acc[6].x = fmaf(rb.z, wj.x, acc[6].x); acc[6].y = fmaf(rb.z, wj.y, acc[6].y);
            acc[7].x = fmaf(rb.w, wj.x, acc[7].x); acc[7].y = fmaf(rb.w, wj.y, acc[7].y);
        }
    }
    // per-wave partials -> LDS
    float2* rp = reinterpret_cast<float2*>(red) + wv * 512 + lane;
#pragma unroll
    for (int r = 0; r < 8; ++r) rp[r * 64] = acc[r];
    __syncthreads();
    // reduce 4 waves, add bias, write out
#pragma unroll
    for (int j = 0; j < 4; ++j) {
        int idx = j * 256 + tid;                  // r*128 + k
        int r = idx >> 7, k = idx & 127;
        float s = red[idx] + red[idx + 1024] + red[idx + 2048] + red[idx + 3072];
        if (k < K_CLS) out[(size_t)(r0 + r) * K_CLS + k] = s + bf[k];
    }
}

extern "C" void kernel_launch(void* const* d_in, const int* in_sizes, int n_in,
                              void* d_out, int out_size, void* d_ws, size_t ws_size,
                              hipStream_t stream) {
    (void)in_sizes; (void)n_in; (void)out_size; (void)ws_size;
    const float* feats = (const float*)d_in[0];
    const float* convw = (const float*)d_in[1];
    const float* gamma = (const float*)d_in[2];
    const float* beta  = (const float*)d_in[3];
    const float* linw  = (const float*)d_in[4];
    const float* linb  = (const float*)d_in[5];
    const float* fcw   = (const float*)d_in[6];
    const float* fcb   = (const float*)d_in[7];
    float* out = (float*)d_out;

    float* ws   = (float*)d_ws;
    float* sig  = ws;                                   // 2048*1088
    float* psum = sig + (size_t)N_B * F_PAD;            // 32*1088
    float* psq  = psum + (size_t)SY * F_PAD;            // 32*1088
    float* Av   = psq + (size_t)SY * F_PAD;             // 1088
    float* Bv   = Av + F_PAD;                           // 1088
    float* tvec = Bv + F_PAD;                           // 1056
    float* part = tvec + F_SIG;                         // 8*112*1056
    float* WfT  = part + (size_t)OSPLIT * KW_PAD * F_SIG;// 1056*128
    float* bfv  = WfT + (size_t)F_SIG * K_PAD;          // 128
    unsigned short* Ahi = (unsigned short*)(bfv + K_PAD);   // 36*512 ushort
    unsigned short* Alo = Ahi + 36 * 512;

    k_wt<<<72, 256, 0, stream>>>(convw, Ahi, Alo);
    k_convsig<<<N_B, 256, 0, stream>>>(feats, Ahi, Alo, sig);
    k_stats<<<dim3(5, SY), 256, 0, stream>>>(sig, psum, psq);
    k_ab<<<5, 256, 0, stream>>>(psum, psq, gamma, beta, Av, Bv);
    k_t<<<F_SIG, 256, 0, stream>>>(linw, Bv, linb, tvec);
    k_wf<<<dim3(5, 7, OSPLIT), 256, 0, stream>>>(fcw, linw, part);
    k_wfred<<<dim3(17, K_PAD), 64, 0, stream>>>(part, Av, WfT);
    k_bf<<<K_PAD, 256, 0, stream>>>(fcw, tvec, fcb, bfv);
    k_out3<<<N_B / 8, 256, 0, stream>>>(sig, WfT, bfv, out);
}

// Round 9
// 96.703 us; speedup vs baseline: 1.4929x; 1.2170x over previous
//
#include <hip/hip_runtime.h>

#define N_B   2048
#define F_SIG 1056
#define F_PAD 1088
#define K_CLS 100
#define K_PAD 128
#define KW_PAD 112         // k rows allocated in part[] (7 y-blocks x 16)
#define DROW   52          // 49 real + 3 pad, 16B-aligned rows
#define OSPLIT  8
#define OCHUNK 132
#define XW     72          // ushorts per padded-position row (16B-mult, bank-spread)
#define SY     32          // k_stats partial row-groups

typedef __attribute__((ext_vector_type(8))) short s8v;     // 8 bf16 in 4 VGPRs
typedef __attribute__((ext_vector_type(4))) float f4v;

__device__ __host__ __forceinline__ void split_bf16(float x, unsigned& h, unsigned& l) {
    unsigned u = __builtin_bit_cast(unsigned, x);
    unsigned hb = (u + 0x7FFFu + ((u >> 16) & 1u)) >> 16;
    float hf = __builtin_bit_cast(float, hb << 16);
    float r = x - hf;
    unsigned ur = __builtin_bit_cast(unsigned, r);
    unsigned lb = (ur + 0x7FFFu + ((ur >> 16) & 1u)) >> 16;
    h = hb & 0xFFFFu; l = lb & 0xFFFFu;
}

// ---------- prepack conv weights into MFMA A-fragments (hi/lo split) ----------
// frag f = ((tap*2+ch)*2+mt); element (lane,e): oc = mt*16+(lane&15),
// cin = ch*32+(lane>>4)*8+e, value = cw[oc][cin][tap]   (layout verified R4)
__global__ void k_wt(const float* __restrict__ cw, unsigned short* __restrict__ Ahi,
                     unsigned short* __restrict__ Alo) {
    int t = blockIdx.x * 256 + threadIdx.x;
    if (t >= 36 * 512) return;
    int f = t >> 9, r = t & 511, lane = r >> 3, e = r & 7;
    int mt = f & 1, ch = (f >> 1) & 1, tap = f >> 2;
    int oc  = mt * 16 + (lane & 15);
    int cin = ch * 32 + (lane >> 4) * 8 + e;
    float v = cw[oc * 576 + cin * 9 + tap];
    unsigned h, l;
    split_bf16(v, h, l);
    Ahi[t] = (unsigned short)h;
    Alo[t] = (unsigned short)l;
}

// ---------- MFMA conv(64->32,3x3,pad1) + Zhang signature depth-2, one image/block ----------
__launch_bounds__(256, 4)
__global__ void k_convsig(const float* __restrict__ x,
                          const unsigned short* __restrict__ Ahi,
                          const unsigned short* __restrict__ Alo,
                          float* __restrict__ sig) {
    __shared__ __align__(16) unsigned short xhi[100 * XW];   // [pad_pos][cin] hi-plane
    __shared__ __align__(16) unsigned short xlo[100 * XW];   // lo-plane
    __shared__ __align__(16) float ysT[64 * 36];             // [pos][oc] stride 36
    float* Ds   = (float*)xhi;          // 32*52   (x planes dead after conv)
    float* Cs   = Ds + 1664;            // 32*52   in-place -> strict 2D prefix P
    float* colS = Cs + 1664;            // 32*8    column sums for level-1
    const int tid = threadIdx.x;
    const int b = blockIdx.x;

    // --- stage: zero planes, then split/scatter feats (position-major) ---
    {
        unsigned* zh = (unsigned*)xhi;
        unsigned* zl = (unsigned*)xlo;
        for (int e = tid; e < 100 * XW / 2; e += 256) { zh[e] = 0u; zl[e] = 0u; }
    }
    __syncthreads();
    const float4* xb4 = reinterpret_cast<const float4*>(x + (size_t)b * 4096);
    {
        float4 v0 = xb4[tid], v1 = xb4[tid + 256], v2 = xb4[tid + 512], v3 = xb4[tid + 768];
#pragma unroll
        for (int u = 0; u < 4; ++u) {
            float4 v = (u == 0) ? v0 : (u == 1) ? v1 : (u == 2) ? v2 : v3;
            int e = tid + u * 256;
            int cin = e >> 4, p = (e & 15) * 4;
            int ih = p >> 3, iw = p & 7;                   // iw in {0,4}
            int pp = (ih + 1) * 10 + (iw + 1);
            unsigned h, l;
            split_bf16(v.x, h, l); xhi[(pp+0)*XW + cin] = (unsigned short)h; xlo[(pp+0)*XW + cin] = (unsigned short)l;
            split_bf16(v.y, h, l); xhi[(pp+1)*XW + cin] = (unsigned short)h; xlo[(pp+1)*XW + cin] = (unsigned short)l;
            split_bf16(v.z, h, l); xhi[(pp+2)*XW + cin] = (unsigned short)h; xlo[(pp+2)*XW + cin] = (unsigned short)l;
            split_bf16(v.w, h, l); xhi[(pp+3)*XW + cin] = (unsigned short)h; xlo[(pp+3)*XW + cin] = (unsigned short)l;
        }
    }
    __syncthreads();

    // --- MFMA conv: wave = one n-tile of 16 positions, 32 oc; A double-buffered ---
    {
        const int wv = tid >> 6;
        const int lane = tid & 63;
        const int j16 = lane & 15, kg = lane >> 4;
        const int p2 = wv * 16 + j16;
        const int oh = p2 >> 3, ow = p2 & 7;
        const unsigned short* Hb = xhi + (oh * 10 + ow) * XW + kg * 8;
        const unsigned short* Lb = xlo + (oh * 10 + ow) * XW + kg * 8;
        const uint4* AH = reinterpret_cast<const uint4*>(Ahi) + lane;  // frag f at +f*64
        const uint4* AL = reinterpret_cast<const uint4*>(Alo) + lane;
        f4v acc0 = {0.f, 0.f, 0.f, 0.f};
        f4v acc1 = {0.f, 0.f, 0.f, 0.f};
        uint4 a0h = AH[0], a0l = AL[0], a1h = AH[64], a1l = AL[64];
#pragma unroll
        for (int k = 0; k < 18; ++k) {
            const int tap = k >> 1, ch = k & 1;
            const int th = tap / 3, tw = tap % 3;          // fold at compile time
            const int xoff = (th * 10 + tw) * XW + ch * 32;
            uint4 bh = *reinterpret_cast<const uint4*>(Hb + xoff);
            uint4 bl = *reinterpret_cast<const uint4*>(Lb + xoff);
            uint4 n0h, n0l, n1h, n1l;
            if (k < 17) {
                const int kn = k + 1;
                const int fn = ((kn >> 1) * 2 + (kn & 1)) * 2;
                n0h = AH[fn * 64];      n0l = AL[fn * 64];
                n1h = AH[fn * 64 + 64]; n1l = AL[fn * 64 + 64];
            }
            s8v Bh = __builtin_bit_cast(s8v, bh);
            s8v Bl = __builtin_bit_cast(s8v, bl);
            s8v A0h = __builtin_bit_cast(s8v, a0h);
            s8v A0l = __builtin_bit_cast(s8v, a0l);
            s8v A1h = __builtin_bit_cast(s8v, a1h);
            s8v A1l = __builtin_bit_cast(s8v, a1l);
            acc0 = __builtin_amdgcn_mfma_f32_16x16x32_bf16(A0h, Bh, acc0, 0, 0, 0);
            acc0 = __builtin_amdgcn_mfma_f32_16x16x32_bf16(A0h, Bl, acc0, 0, 0, 0);
            acc0 = __builtin_amdgcn_mfma_f32_16x16x32_bf16(A0l, Bh, acc0, 0, 0, 0);
            acc1 = __builtin_amdgcn_mfma_f32_16x16x32_bf16(A1h, Bh, acc1, 0, 0, 0);
            acc1 = __builtin_amdgcn_mfma_f32_16x16x32_bf16(A1h, Bl, acc1, 0, 0, 0);
            acc1 = __builtin_amdgcn_mfma_f32_16x16x32_bf16(A1l, Bh, acc1, 0, 0, 0);
            if (k < 17) { a0h = n0h; a0l = n0l; a1h = n1h; a1l = n1l; }
        }
        // C/D: col=lane&15 -> pos, row=(lane>>4)*4+reg -> oc
        *reinterpret_cast<f4v*>(ysT + p2 * 36 + kg * 4)      = acc0;
        *reinterpret_cast<f4v*>(ysT + p2 * 36 + 16 + kg * 4) = acc1;
    }
    __syncthreads();

    // --- fused D + strict column scan; thread = (c, j) ---
    if (tid < 224) {
        const int c = tid / 7, j = tid - (tid / 7) * 7;
        float a  = ysT[j * 36 + c];            // ys[0][j]
        float bq = ysT[(j + 1) * 36 + c];      // ys[0][j+1]
        float run = 0.f;
        float* Dc = Ds + c * DROW;
        float* Cc = Cs + c * DROW;
#pragma unroll
        for (int i = 0; i < 7; ++i) {
            float a2 = ysT[((i + 1) * 8 + j) * 36 + c];
            float b2 = ysT[((i + 1) * 8 + j + 1) * 36 + c];
            float d = (b2 - a2) - (bq - a);
            Dc[i * 7 + j] = d;
            Cc[i * 7 + j] = run;               // strict prefix along i
            run += d;
            a = a2; bq = b2;
        }
        colS[c * 8 + j] = run;                 // full column sum (for level-1)
    } else {
        const int c = tid - 224;               // zero D row pads
        Ds[c * DROW + 49] = 0.f; Ds[c * DROW + 50] = 0.f; Ds[c * DROW + 51] = 0.f;
    }
    __syncthreads();

    // --- in-place strict row scan: Cs becomes strict 2D prefix P; thread = (c, i) ---
    if (tid < 224) {
        const int c = tid / 7, i = tid - (tid / 7) * 7;
        float* Cc = Cs + c * DROW + i * 7;
        float run = 0.f;
#pragma unroll
        for (int j = 0; j < 7; ++j) {
            float v = Cc[j];
            Cc[j] = run;
            run += v;
        }
    } else {
        const int c = tid - 224;               // zero P row pads
        Cs[c * DROW + 49] = 0.f; Cs[c * DROW + 50] = 0.f; Cs[c * DROW + 51] = 0.f;
    }
    __syncthreads();

    // --- level-2: 2x2 register-blocked, vectorized LDS reads (P = Cs) ---
    {
        const int bc1 = tid >> 4, bc2 = tid & 15;
        const float* P0 = Cs + bc1 * DROW;
        const float* P1 = Cs + (bc1 + 16) * DROW;
        const float* D0 = Ds + bc2 * DROW;
        const float* D1 = Ds + (bc2 + 16) * DROW;
        float a00 = 0.f, a01 = 0.f, a10 = 0.f, a11 = 0.f;
#pragma unroll
        for (int qb = 0; qb < DROW; qb += 4) {
            float4 p0 = *reinterpret_cast<const float4*>(P0 + qb);
            float4 p1 = *reinterpret_cast<const float4*>(P1 + qb);
            float4 d0 = *reinterpret_cast<const float4*>(D0 + qb);
            float4 d1 = *reinterpret_cast<const float4*>(D1 + qb);
            a00 += p0.x*d0.x + p0.y*d0.y + p0.z*d0.z + p0.w*d0.w;
            a01 += p0.x*d1.x + p0.y*d1.y + p0.z*d1.z + p0.w*d1.w;
            a10 += p1.x*d0.x + p1.y*d0.y + p1.z*d0.z + p1.w*d0.w;
            a11 += p1.x*d1.x + p1.y*d1.y + p1.z*d1.z + p1.w*d1.w;
        }
        float* so = sig + (size_t)b * F_PAD + 32;
        so[bc1 * 32 + bc2]               = a00;
        so[bc1 * 32 + (bc2 + 16)]        = a01;
        so[(bc1 + 16) * 32 + bc2]        = a10;
        so[(bc1 + 16) * 32 + (bc2 + 16)] = a11;
    }

    // --- level-1 from column sums + zero sig pad ---
    if (tid < 32) {
        const float* cr = colS + tid * 8;
        float s = cr[0] + cr[1] + cr[2] + cr[3] + cr[4] + cr[5] + cr[6];
        sig[(size_t)b * F_PAD + tid] = s;
    } else if (tid < 64) {
        sig[(size_t)b * F_PAD + F_SIG + (tid - 32)] = 0.f;
    }
}

// ---------- per-feature partial sum / sumsq (no atomics, no init, 4-row ILP) ----------
__global__ void k_stats(const float* __restrict__ sig, float* __restrict__ psum,
                        float* __restrict__ psq) {
    int f = blockIdx.x * 256 + threadIdx.x;
    if (f >= F_SIG) return;
    int y = blockIdx.y;
    const float* sp = sig + (size_t)(y * 64) * F_PAD + f;
    float s = 0.f, q = 0.f;
    for (int r = 0; r < 64; r += 4) {
        float v0 = sp[(size_t)(r + 0) * F_PAD];
        float v1 = sp[(size_t)(r + 1) * F_PAD];
        float v2 = sp[(size_t)(r + 2) * F_PAD];
        float v3 = sp[(size_t)(r + 3) * F_PAD];
        s += v0 + v1 + v2 + v3;
        q = fmaf(v0, v0, q); q = fmaf(v1, v1, q);
        q = fmaf(v2, v2, q); q = fmaf(v3, v3, q);
    }
    psum[(size_t)y * F_PAD + f] = s;
    psq[(size_t)y * F_PAD + f]  = q;
}

// ---------- BN fold (reduces the 32 partials) ----------
__global__ void k_ab(const float* __restrict__ psum, const float* __restrict__ psq,
                     const float* __restrict__ gamma, const float* __restrict__ beta,
                     float* __restrict__ Av, float* __restrict__ Bv) {
    int i = blockIdx.x * 256 + threadIdx.x;
    if (i >= F_PAD) return;
    float a = 0.f, bb = 0.f;
    if (i < F_SIG) {
        float s = 0.f, q = 0.f;
#pragma unroll
        for (int z = 0; z < SY; ++z) {
            s += psum[(size_t)z * F_PAD + i];
            q += psq[(size_t)z * F_PAD + i];
        }
        float m   = s * (1.f / 2048.f);
        float var = q * (1.f / 2048.f) - m * m;
        a  = gamma[i] / sqrtf(var + 1e-5f);
        bb = beta[i] - m * a;
    }
    Av[i] = a;
    Bv[i] = bb;
}

// ---------- t[o] = lin_b[o] + sum_i Bv[i]*lin_w[o,i] ----------
__global__ void k_t(const float* __restrict__ lw, const float* __restrict__ Bv,
                    const float* __restrict__ lb, float* __restrict__ tvec) {
    int o = blockIdx.x, tid = threadIdx.x;
    const float* lr = lw + (size_t)o * F_SIG;
    float s = 0.f;
    for (int i = tid; i < F_SIG; i += 256) s = fmaf(Bv[i], lr[i], s);
#pragma unroll
    for (int d = 32; d; d >>= 1) s += __shfl_xor(s, d);
    __shared__ float red[4];
    if ((tid & 63) == 0) red[tid >> 6] = s;
    __syncthreads();
    if (tid == 0) tvec[o] = lb[o] + red[0] + red[1] + red[2] + red[3];
}

#define WF_FMA16(sv, vv) do { \
    A0.x = fmaf((sv).x, (vv).x, A0.x); A0.y = fmaf((sv).x, (vv).y, A0.y); \
    A0.z = fmaf((sv).x, (vv).z, A0.z); A0.w = fmaf((sv).x, (vv).w, A0.w); \
    A1.x = fmaf((sv).y, (vv).x, A1.x); A1.y = fmaf((sv).y, (vv).y, A1.y); \
    A1.z = fmaf((sv).y, (vv).z, A1.z); A1.w = fmaf((sv).y, (vv).w, A1.w); \
    A2.x = fmaf((sv).z, (vv).x, A2.x); A2.y = fmaf((sv).z, (vv).y, A2.y); \
    A2.z = fmaf((sv).z, (vv).z, A2.z); A2.w = fmaf((sv).z, (vv).w, A2.w); \
    A3.x = fmaf((sv).w, (vv).x, A3.x); A3.y = fmaf((sv).w, (vv).y, A3.y); \
    A3.z = fmaf((sv).w, (vv).z, A3.z); A3.w = fmaf((sv).w, (vv).w, A3.w); } while (0)

// ---------- split-K partials: part[z][k][i] = sum_{o in chunk z} fcw[k,o]*lin_w[o,i]
// 16 k/block (4 per wave); manual 4-o unroll -> 8 named loads in flight before FMAs.
// sv_r = fcw[k0+r][o..o+3] (contiguous); A_r accumulates along the same k-row r.
// A_r[c] pairs sv_r.{x,y,z,w} with v{0,1,2,3}: A_r = sum_j sv_r[j] * v_j  elementwise over c.
__launch_bounds__(256)
__global__ void k_wf(const float* __restrict__ fcw, const float* __restrict__ lw,
                     float* __restrict__ part) {
    const int wv = threadIdx.x >> 6;
    const int k0 = blockIdx.y * 16 + wv * 4;        // this wave's four k rows
    const int z  = blockIdx.z;
    const int ib = blockIdx.x * 256 + (threadIdx.x & 63) * 4;
    if (ib >= F_SIG) return;
    const float* f0 = fcw + (size_t)min(k0,     K_CLS - 1) * F_SIG;
    const float* f1 = fcw + (size_t)min(k0 + 1, K_CLS - 1) * F_SIG;
    const float* f2 = fcw + (size_t)min(k0 + 2, K_CLS - 1) * F_SIG;
    const float* f3 = fcw + (size_t)min(k0 + 3, K_CLS - 1) * F_SIG;
    const int o0 = z * OCHUNK;
    float4 A0 = {0.f,0.f,0.f,0.f}, A1 = {0.f,0.f,0.f,0.f};
    float4 A2 = {0.f,0.f,0.f,0.f}, A3 = {0.f,0.f,0.f,0.f};
    const float* lwb = lw + (size_t)o0 * F_SIG + ib;
    for (int g = 0; g < OCHUNK / 4; ++g) {
        const int o = o0 + g * 4;
        // issue all 8 independent 16B loads before any consumer
        float4 s0 = *reinterpret_cast<const float4*>(f0 + o);
        float4 s1 = *reinterpret_cast<const float4*>(f1 + o);
        float4 s2 = *reinterpret_cast<const float4*>(f2 + o);
        float4 s3 = *reinterpret_cast<const float4*>(f3 + o);
        const float* lp = lwb + (size_t)(g * 4) * F_SIG;
        float4 v0 = *reinterpret_cast<const float4*>(lp);
        float4 v1 = *reinterpret_cast<const float4*>(lp + F_SIG);
        float4 v2 = *reinterpret_cast<const float4*>(lp + 2 * F_SIG);
        float4 v3 = *reinterpret_cast<const float4*>(lp + 3 * F_SIG);
        // A_r += s_r.x*v0 + s_r.y*v1 + s_r.z*v2 + s_r.w*v3
        float4 sj0 = make_float4(s0.x, s1.x, s2.x, s3.x);
        float4 sj1 = make_float4(s0.y, s1.y, s2.y, s3.y);
        float4 sj2 = make_float4(s0.z, s1.z, s2.z, s3.z);
        float4 sj3 = make_float4(s0.w, s1.w, s2.w, s3.w);
        WF_FMA16(sj0, v0);
        WF_FMA16(sj1, v1);
        WF_FMA16(sj2, v2);
        WF_FMA16(sj3, v3);
    }
    *reinterpret_cast<float4*>(part + ((size_t)z * KW_PAD + k0 + 0) * F_SIG + ib) = A0;
    *reinterpret_cast<float4*>(part + ((size_t)z * KW_PAD + k0 + 1) * F_SIG + ib) = A1;
    *reinterpret_cast<float4*>(part + ((size_t)z * KW_PAD + k0 + 2) * F_SIG + ib) = A2;
    *reinterpret_cast<float4*>(part + ((size_t)z * KW_PAD + k0 + 3) * F_SIG + ib) = A3;
}

// ---------- reduce partials, fold Av, emit WfT[i*128 + k] ----------
__launch_bounds__(64)
__global__ void k_wfred(const float* __restrict__ part, const float* __restrict__ Av,
                        float* __restrict__ WfT) {
    const int i = blockIdx.x * 64 + threadIdx.x;
    const int k = blockIdx.y;
    if (i >= F_SIG) return;
    float w = 0.f;
    if (k < K_CLS) {
        float s = 0.f;
#pragma unroll
        for (int z = 0; z < OSPLIT; ++z)
            s += part[((size_t)z * KW_PAD + k) * F_SIG + i];
        w = Av[i] * s;
    }
    WfT[(size_t)i * K_PAD + k] = w;
}

// ---------- bf[k] = fc_b[k] + sum_o fc_w[k,o]*t[o] ----------
__global__ void k_bf(const float* __restrict__ fcw, const float* __restrict__ tvec,
                     const float* __restrict__ fcb, float* __restrict__ bf) {
    int k = blockIdx.x, tid = threadIdx.x;
    float s = 0.f;
    if (k < K_CLS) {
        const float* fr = fcw + (size_t)k * F_SIG;
        for (int o = tid; o < F_SIG; o += 256) s = fmaf(fr[o], tvec[o], s);
    }
#pragma unroll
    for (int d = 32; d; d >>= 1) s += __shfl_xor(s, d);
    __shared__ float red[4];
    if ((tid & 63) == 0) red[tid >> 6] = s;
    __syncthreads();
    if (tid == 0) {
        float tot = red[0] + red[1] + red[2] + red[3];
        bf[k] = (k < K_CLS) ? (tot + fcb[k]) : 0.f;
    }
}

// ---------- out[r,k]: 8 rows/block, waves split i-range, W read once per block ----------
__launch_bounds__(256)
__global__ void k_out3(const float* __restrict__ sig, const float* __restrict__ WfT,
                       const float* __restrict__ bf, float* __restrict__ out) {
    __shared__ __align__(16) float slT[F_SIG * 8];   // [i][row] 33.8 KB
    __shared__ __align__(16) float red[4 * 8 * K_PAD]; // 16 KB
    const int tid = threadIdx.x;
    const int r0 = blockIdx.x * 8;
    // stage 8 sig rows transposed: slT[i][row]
    for (int e = tid; e < 8 * (F_SIG / 4); e += 256) {
        int row = e & 7, c4 = e >> 3;
        float4 v = *reinterpret_cast<const float4*>(sig + (size_t)(r0 + row) * F_PAD + c4 * 4);
        slT[(c4 * 4 + 0) * 8 + row] = v.x;
        slT[(c4 * 4 + 1) * 8 + row] = v.y;
        slT[(c4 * 4 + 2) * 8 + row] = v.z;
        slT[(c4 * 4 + 3) * 8 + row] = v.w;
    }
    __syncthreads();

    const int wv = tid >> 6, lane = tid & 63;
    const int i0 = wv * 264;
    const float2* Wp = reinterpret_cast<const float2*>(WfT) + lane;  // row i at +i*64
    float2 acc[8];
#pragma unroll
    for (int r = 0; r < 8; ++r) acc[r] = make_float2(0.f, 0.f);
    for (int g = 0; g < 33; ++g) {
        const int ib = i0 + g * 8;
        float2 w0 = Wp[(size_t)(ib + 0) * 64];
        float2 w1 = Wp[(size_t)(ib + 1) * 64];
        float2 w2 = Wp[(size_t)(ib + 2) * 64];
        float2 w3 = Wp[(size_t)(ib + 3) * 64];
        float2 w4 = Wp[(size_t)(ib + 4) * 64];
        float2 w5 = Wp[(size_t)(ib + 5) * 64];
        float2 w6 = Wp[(size_t)(ib + 6) * 64];
        float2 w7 = Wp[(size_t)(ib + 7) * 64];
#pragma unroll
        for (int j = 0; j < 8; ++j) {
            float2 wj = (j == 0) ? w0 : (j == 1) ? w1 : (j == 2) ? w2 : (j == 3) ? w3
                      : (j == 4) ? w4 : (j == 5) ? w5 : (j == 6) ? w6 : w7;
            const float4* sp = reinterpret_cast<const float4*>(slT + (ib + j) * 8);
            float4 ra = sp[0], rb = sp[1];
            acc[0].x = fmaf(ra.x, wj.x, acc[0].x); acc[0].y = fmaf(ra.x, wj.y, acc[0].y);
            acc[1].x = fmaf(ra.y, wj.x, acc[1].x); acc[1].y = fmaf(ra.y, wj.y, acc[1].y);
            acc[2].x = fmaf(ra.z, wj.x, acc[2].x); acc[2].y = fmaf(ra.z, wj.y, acc[2].y);
            acc[3].x = fmaf(ra.w, wj.x, acc[3].x); acc[3].y = fmaf(ra.w, wj.y, acc[3].y);
            acc[4].x = fmaf(rb.x, wj.x, acc[4].x); acc[4].y = fmaf(rb.x, wj.y, acc[4].y);
            acc[5].x = fmaf(rb.y, wj.x, acc[5].x); acc[5].y = fmaf(rb.y, wj.y, acc[5].y);
            acc[6].x = fmaf(rb.z, wj.x, acc[6].x); acc[6].y = fmaf(rb.z, wj.y, acc[6].y);
            acc[7].x = fmaf(rb.w, wj.x, acc[7].x); acc[7].y = fmaf(rb.w, wj.y, acc[7].y);
        }
    }
    // per-wave partials -> LDS
    float2* rp = reinterpret_cast<float2*>(red) + wv * 512 + lane;
#pragma unroll
    for (int r = 0; r < 8; ++r) rp[r * 64] = acc[r];
    __syncthreads();
    // reduce 4 waves, add bias, write out
#pragma unroll
    for (int j = 0; j < 4; ++j) {
        int idx = j * 256 + tid;                  // r*128 + k
        int r = idx >> 7, k = idx & 127;
        float s = red[idx] + red[idx + 1024] + red[idx + 2048] + red[idx + 3072];
        if (k < K_CLS) out[(size_t)(r0 + r) * K_CLS + k] = s + bf[k];
    }
}

extern "C" void kernel_launch(void* const* d_in, const int* in_sizes, int n_in,
                              void* d_out, int out_size, void* d_ws, size_t ws_size,
                              hipStream_t stream) {
    (void)in_sizes; (void)n_in; (void)out_size; (void)ws_size;
    const float* feats = (const float*)d_in[0];
    const float* convw = (const float*)d_in[1];
    const float* gamma = (const float*)d_in[2];
    const float* beta  = (const float*)d_in[3];
    const float* linw  = (const float*)d_in[4];
    const float* linb  = (const float*)d_in[5];
    const float* fcw   = (const float*)d_in[6];
    const float* fcb   = (const float*)d_in[7];
    float* out = (float*)d_out;

    float* ws   = (float*)d_ws;
    float* sig  = ws;                                   // 2048*1088
    float* psum = sig + (size_t)N_B * F_PAD;            // 32*1088
    float* psq  = psum + (size_t)SY * F_PAD;            // 32*1088
    float* Av   = psq + (size_t)SY * F_PAD;             // 1088
    float* Bv   = Av + F_PAD;                           // 1088
    float* tvec = Bv + F_PAD;                           // 1056
    float* part = tvec + F_SIG;                         // 8*112*1056
    float* WfT  = part + (size_t)OSPLIT * KW_PAD * F_SIG;// 1056*128
    float* bfv  = WfT + (size_t)F_SIG * K_PAD;          // 128
    unsigned short* Ahi = (unsigned short*)(bfv + K_PAD);   // 36*512 ushort
    unsigned short* Alo = Ahi + 36 * 512;

    k_wt<<<72, 256, 0, stream>>>(convw, Ahi, Alo);
    k_convsig<<<N_B, 256, 0, stream>>>(feats, Ahi, Alo, sig);
    k_stats<<<dim3(5, SY), 256, 0, stream>>>(sig, psum, psq);
    k_ab<<<5, 256, 0, stream>>>(psum, psq, gamma, beta, Av, Bv);
    k_t<<<F_SIG, 256, 0, stream>>>(linw, Bv, linb, tvec);
    k_wf<<<dim3(5, 7, OSPLIT), 256, 0, stream>>>(fcw, linw, part);
    k_wfred<<<dim3(17, K_PAD), 64, 0, stream>>>(part, Av, WfT);
    k_bf<<<K_PAD, 256, 0, stream>>>(fcw, tvec, fcb, bfv);
    k_out3<<<N_B / 8, 256, 0, stream>>>(sig, WfT, bfv, out);
}

// Round 10
// 87.251 us; speedup vs baseline: 1.6547x; 1.1083x over previous
//
#include <hip/hip_runtime.h>

#define N_B   2048
#define F_SIG 1056
#define F_PAD 1088
#define K_CLS 100
#define K_PAD 128
#define KW_PAD 112         // k rows allocated in part[] (7 y-blocks x 16)
#define DROW   52          // 49 real + 3 pad, 16B-aligned rows
#define OSPLIT  8
#define OCHUNK 132
#define XW     72          // ushorts per padded-position row (16B-mult, bank-spread)
#define SY     32          // k_stats partial row-groups
#define WF_BLKS 280        // 5 x 7 x 8
#define BF0_BLKS 128

typedef __attribute__((ext_vector_type(8))) short s8v;     // 8 bf16 in 4 VGPRs
typedef __attribute__((ext_vector_type(4))) float f4v;

__device__ __host__ __forceinline__ void split_bf16(float x, unsigned& h, unsigned& l) {
    unsigned u = __builtin_bit_cast(unsigned, x);
    unsigned hb = (u + 0x7FFFu + ((u >> 16) & 1u)) >> 16;
    float hf = __builtin_bit_cast(float, hb << 16);
    float r = x - hf;
    unsigned ur = __builtin_bit_cast(unsigned, r);
    unsigned lb = (ur + 0x7FFFu + ((ur >> 16) & 1u)) >> 16;
    h = hb & 0xFFFFu; l = lb & 0xFFFFu;
}

// ---------- prepack conv weights into MFMA A-fragments (hi/lo split) ----------
__global__ void k_wt(const float* __restrict__ cw, unsigned short* __restrict__ Ahi,
                     unsigned short* __restrict__ Alo) {
    int t = blockIdx.x * 256 + threadIdx.x;
    if (t >= 36 * 512) return;
    int f = t >> 9, r = t & 511, lane = r >> 3, e = r & 7;
    int mt = f & 1, ch = (f >> 1) & 1, tap = f >> 2;
    int oc  = mt * 16 + (lane & 15);
    int cin = ch * 32 + (lane >> 4) * 8 + e;
    float v = cw[oc * 576 + cin * 9 + tap];
    unsigned h, l;
    split_bf16(v, h, l);
    Ahi[t] = (unsigned short)h;
    Alo[t] = (unsigned short)l;
}

#define WF_FMA16(sv, vv) do { \
    A0.x = fmaf((sv).x, (vv).x, A0.x); A0.y = fmaf((sv).x, (vv).y, A0.y); \
    A0.z = fmaf((sv).x, (vv).z, A0.z); A0.w = fmaf((sv).x, (vv).w, A0.w); \
    A1.x = fmaf((sv).y, (vv).x, A1.x); A1.y = fmaf((sv).y, (vv).y, A1.y); \
    A1.z = fmaf((sv).y, (vv).z, A1.z); A1.w = fmaf((sv).y, (vv).w, A1.w); \
    A2.x = fmaf((sv).z, (vv).x, A2.x); A2.y = fmaf((sv).z, (vv).y, A2.y); \
    A2.z = fmaf((sv).z, (vv).z, A2.z); A2.w = fmaf((sv).z, (vv).w, A2.w); \
    A3.x = fmaf((sv).w, (vv).x, A3.x); A3.y = fmaf((sv).w, (vv).y, A3.y); \
    A3.z = fmaf((sv).w, (vv).z, A3.z); A3.w = fmaf((sv).w, (vv).w, A3.w); } while (0)

// ---------- FUSED: [0,280) split-K fcw@lw partials | [280,408) bf0 | [408,2456) conv+sig ----------
__launch_bounds__(256, 4)
__global__ void k_fused(const float* __restrict__ x,
                        const unsigned short* __restrict__ Ahi,
                        const unsigned short* __restrict__ Alo,
                        float* __restrict__ sig,
                        const float* __restrict__ fcw, const float* __restrict__ lw,
                        float* __restrict__ part,
                        const float* __restrict__ linb, const float* __restrict__ fcb,
                        float* __restrict__ bfv) {
    __shared__ __align__(16) unsigned short xhi[100 * XW];   // [pad_pos][cin] hi-plane
    __shared__ __align__(16) unsigned short xlo[100 * XW];   // lo-plane
    __shared__ __align__(16) float ysT[64 * 36];             // [pos][oc] stride 36
    const int tid = threadIdx.x;
    const int bid = blockIdx.x;

    if (bid < WF_BLKS) {
        // ===== k_wf body: part[z][k][i] = sum_{o in chunk z} fcw[k,o]*lin_w[o,i] =====
        const int ibx = bid % 5, ky = (bid / 5) % 7, z = bid / 35;
        const int wv = tid >> 6;
        const int k0 = ky * 16 + wv * 4;
        const int ib = ibx * 256 + (tid & 63) * 4;
        if (ib >= F_SIG) return;
        const float* f0 = fcw + (size_t)min(k0,     K_CLS - 1) * F_SIG;
        const float* f1 = fcw + (size_t)min(k0 + 1, K_CLS - 1) * F_SIG;
        const float* f2 = fcw + (size_t)min(k0 + 2, K_CLS - 1) * F_SIG;
        const float* f3 = fcw + (size_t)min(k0 + 3, K_CLS - 1) * F_SIG;
        const int o0 = z * OCHUNK;
        float4 A0 = {0.f,0.f,0.f,0.f}, A1 = {0.f,0.f,0.f,0.f};
        float4 A2 = {0.f,0.f,0.f,0.f}, A3 = {0.f,0.f,0.f,0.f};
        const float* lwb = lw + (size_t)o0 * F_SIG + ib;
        for (int g = 0; g < OCHUNK / 4; ++g) {
            const int o = o0 + g * 4;
            float4 s0 = *reinterpret_cast<const float4*>(f0 + o);
            float4 s1 = *reinterpret_cast<const float4*>(f1 + o);
            float4 s2 = *reinterpret_cast<const float4*>(f2 + o);
            float4 s3 = *reinterpret_cast<const float4*>(f3 + o);
            const float* lp = lwb + (size_t)(g * 4) * F_SIG;
            float4 v0 = *reinterpret_cast<const float4*>(lp);
            float4 v1 = *reinterpret_cast<const float4*>(lp + F_SIG);
            float4 v2 = *reinterpret_cast<const float4*>(lp + 2 * F_SIG);
            float4 v3 = *reinterpret_cast<const float4*>(lp + 3 * F_SIG);
            float4 sj0 = make_float4(s0.x, s1.x, s2.x, s3.x);
            float4 sj1 = make_float4(s0.y, s1.y, s2.y, s3.y);
            float4 sj2 = make_float4(s0.z, s1.z, s2.z, s3.z);
            float4 sj3 = make_float4(s0.w, s1.w, s2.w, s3.w);
            WF_FMA16(sj0, v0);
            WF_FMA16(sj1, v1);
            WF_FMA16(sj2, v2);
            WF_FMA16(sj3, v3);
        }
        *reinterpret_cast<float4*>(part + ((size_t)z * KW_PAD + k0 + 0) * F_SIG + ib) = A0;
        *reinterpret_cast<float4*>(part + ((size_t)z * KW_PAD + k0 + 1) * F_SIG + ib) = A1;
        *reinterpret_cast<float4*>(part + ((size_t)z * KW_PAD + k0 + 2) * F_SIG + ib) = A2;
        *reinterpret_cast<float4*>(part + ((size_t)z * KW_PAD + k0 + 3) * F_SIG + ib) = A3;
        return;
    }
    if (bid < WF_BLKS + BF0_BLKS) {
        // ===== bf0: bfv[k] = fcb[k] + sum_o fcw[k,o]*lin_b[o]  (rest added by k_wfred) =====
        const int k = bid - WF_BLKS;
        float s = 0.f;
        if (k < K_CLS) {
            const float* fr = fcw + (size_t)k * F_SIG;
            for (int o = tid; o < F_SIG; o += 256) s = fmaf(fr[o], linb[o], s);
        }
#pragma unroll
        for (int d = 32; d; d >>= 1) s += __shfl_xor(s, d);
        float* redf = (float*)xhi;
        if ((tid & 63) == 0) redf[tid >> 6] = s;
        __syncthreads();
        if (tid == 0) {
            float tot = redf[0] + redf[1] + redf[2] + redf[3];
            bfv[k] = (k < K_CLS) ? (tot + fcb[k]) : 0.f;
        }
        return;
    }

    // ===== convsig body =====
    const int b = bid - (WF_BLKS + BF0_BLKS);
    float* Ds   = (float*)xhi;          // 32*52   (x planes dead after conv)
    float* Cs   = Ds + 1664;            // 32*52   in-place -> strict 2D prefix P
    float* colS = Cs + 1664;            // 32*8    column sums for level-1

    {
        unsigned* zh = (unsigned*)xhi;
        unsigned* zl = (unsigned*)xlo;
        for (int e = tid; e < 100 * XW / 2; e += 256) { zh[e] = 0u; zl[e] = 0u; }
    }
    __syncthreads();
    const float4* xb4 = reinterpret_cast<const float4*>(x + (size_t)b * 4096);
    {
        float4 v0 = xb4[tid], v1 = xb4[tid + 256], v2 = xb4[tid + 512], v3 = xb4[tid + 768];
#pragma unroll
        for (int u = 0; u < 4; ++u) {
            float4 v = (u == 0) ? v0 : (u == 1) ? v1 : (u == 2) ? v2 : v3;
            int e = tid + u * 256;
            int cin = e >> 4, p = (e & 15) * 4;
            int ih = p >> 3, iw = p & 7;                   // iw in {0,4}
            int pp = (ih + 1) * 10 + (iw + 1);
            unsigned h, l;
            split_bf16(v.x, h, l); xhi[(pp+0)*XW + cin] = (unsigned short)h; xlo[(pp+0)*XW + cin] = (unsigned short)l;
            split_bf16(v.y, h, l); xhi[(pp+1)*XW + cin] = (unsigned short)h; xlo[(pp+1)*XW + cin] = (unsigned short)l;
            split_bf16(v.z, h, l); xhi[(pp+2)*XW + cin] = (unsigned short)h; xlo[(pp+2)*XW + cin] = (unsigned short)l;
            split_bf16(v.w, h, l); xhi[(pp+3)*XW + cin] = (unsigned short)h; xlo[(pp+3)*XW + cin] = (unsigned short)l;
        }
    }
    __syncthreads();

    {
        const int wv = tid >> 6;
        const int lane = tid & 63;
        const int j16 = lane & 15, kg = lane >> 4;
        const int p2 = wv * 16 + j16;
        const int oh = p2 >> 3, ow = p2 & 7;
        const unsigned short* Hb = xhi + (oh * 10 + ow) * XW + kg * 8;
        const unsigned short* Lb = xlo + (oh * 10 + ow) * XW + kg * 8;
        const uint4* AH = reinterpret_cast<const uint4*>(Ahi) + lane;  // frag f at +f*64
        const uint4* AL = reinterpret_cast<const uint4*>(Alo) + lane;
        f4v acc0 = {0.f, 0.f, 0.f, 0.f};
        f4v acc1 = {0.f, 0.f, 0.f, 0.f};
        uint4 a0h = AH[0], a0l = AL[0], a1h = AH[64], a1l = AL[64];
#pragma unroll
        for (int k = 0; k < 18; ++k) {
            const int tap = k >> 1, ch = k & 1;
            const int th = tap / 3, tw = tap % 3;          // fold at compile time
            const int xoff = (th * 10 + tw) * XW + ch * 32;
            uint4 bh = *reinterpret_cast<const uint4*>(Hb + xoff);
            uint4 bl = *reinterpret_cast<const uint4*>(Lb + xoff);
            uint4 n0h, n0l, n1h, n1l;
            if (k < 17) {
                const int kn = k + 1;
                const int fn = ((kn >> 1) * 2 + (kn & 1)) * 2;
                n0h = AH[fn * 64];      n0l = AL[fn * 64];
                n1h = AH[fn * 64 + 64]; n1l = AL[fn * 64 + 64];
            }
            s8v Bh = __builtin_bit_cast(s8v, bh);
            s8v Bl = __builtin_bit_cast(s8v, bl);
            s8v A0h = __builtin_bit_cast(s8v, a0h);
            s8v A0l = __builtin_bit_cast(s8v, a0l);
            s8v A1h = __builtin_bit_cast(s8v, a1h);
            s8v A1l = __builtin_bit_cast(s8v, a1l);
            acc0 = __builtin_amdgcn_mfma_f32_16x16x32_bf16(A0h, Bh, acc0, 0, 0, 0);
            acc0 = __builtin_amdgcn_mfma_f32_16x16x32_bf16(A0h, Bl, acc0, 0, 0, 0);
            acc0 = __builtin_amdgcn_mfma_f32_16x16x32_bf16(A0l, Bh, acc0, 0, 0, 0);
            acc1 = __builtin_amdgcn_mfma_f32_16x16x32_bf16(A1h, Bh, acc1, 0, 0, 0);
            acc1 = __builtin_amdgcn_mfma_f32_16x16x32_bf16(A1h, Bl, acc1, 0, 0, 0);
            acc1 = __builtin_amdgcn_mfma_f32_16x16x32_bf16(A1l, Bh, acc1, 0, 0, 0);
            if (k < 17) { a0h = n0h; a0l = n0l; a1h = n1h; a1l = n1l; }
        }
        *reinterpret_cast<f4v*>(ysT + p2 * 36 + kg * 4)      = acc0;
        *reinterpret_cast<f4v*>(ysT + p2 * 36 + 16 + kg * 4) = acc1;
    }
    __syncthreads();

    // fused D + strict column scan; thread = (c, j)
    if (tid < 224) {
        const int c = tid / 7, j = tid - (tid / 7) * 7;
        float a  = ysT[j * 36 + c];
        float bq = ysT[(j + 1) * 36 + c];
        float run = 0.f;
        float* Dc = Ds + c * DROW;
        float* Cc = Cs + c * DROW;
#pragma unroll
        for (int i = 0; i < 7; ++i) {
            float a2 = ysT[((i + 1) * 8 + j) * 36 + c];
            float b2 = ysT[((i + 1) * 8 + j + 1) * 36 + c];
            float d = (b2 - a2) - (bq - a);
            Dc[i * 7 + j] = d;
            Cc[i * 7 + j] = run;
            run += d;
            a = a2; bq = b2;
        }
        colS[c * 8 + j] = run;
    } else {
        const int c = tid - 224;
        Ds[c * DROW + 49] = 0.f; Ds[c * DROW + 50] = 0.f; Ds[c * DROW + 51] = 0.f;
    }
    __syncthreads();

    // in-place strict row scan
    if (tid < 224) {
        const int c = tid / 7, i = tid - (tid / 7) * 7;
        float* Cc = Cs + c * DROW + i * 7;
        float run = 0.f;
#pragma unroll
        for (int j = 0; j < 7; ++j) {
            float v = Cc[j];
            Cc[j] = run;
            run += v;
        }
    } else {
        const int c = tid - 224;
        Cs[c * DROW + 49] = 0.f; Cs[c * DROW + 50] = 0.f; Cs[c * DROW + 51] = 0.f;
    }
    __syncthreads();

    // level-2
    {
        const int bc1 = tid >> 4, bc2 = tid & 15;
        const float* P0 = Cs + bc1 * DROW;
        const float* P1 = Cs + (bc1 + 16) * DROW;
        const float* D0 = Ds + bc2 * DROW;
        const float* D1 = Ds + (bc2 + 16) * DROW;
        float a00 = 0.f, a01 = 0.f, a10 = 0.f, a11 = 0.f;
#pragma unroll
        for (int qb = 0; qb < DROW; qb += 4) {
            float4 p0 = *reinterpret_cast<const float4*>(P0 + qb);
            float4 p1 = *reinterpret_cast<const float4*>(P1 + qb);
            float4 d0 = *reinterpret_cast<const float4*>(D0 + qb);
            float4 d1 = *reinterpret_cast<const float4*>(D1 + qb);
            a00 += p0.x*d0.x + p0.y*d0.y + p0.z*d0.z + p0.w*d0.w;
            a01 += p0.x*d1.x + p0.y*d1.y + p0.z*d1.z + p0.w*d1.w;
            a10 += p1.x*d0.x + p1.y*d0.y + p1.z*d0.z + p1.w*d0.w;
            a11 += p1.x*d1.x + p1.y*d1.y + p1.z*d1.z + p1.w*d1.w;
        }
        float* so = sig + (size_t)b * F_PAD + 32;
        so[bc1 * 32 + bc2]               = a00;
        so[bc1 * 32 + (bc2 + 16)]        = a01;
        so[(bc1 + 16) * 32 + bc2]        = a10;
        so[(bc1 + 16) * 32 + (bc2 + 16)] = a11;
    }

    // level-1 + zero pad
    if (tid < 32) {
        const float* cr = colS + tid * 8;
        float s = cr[0] + cr[1] + cr[2] + cr[3] + cr[4] + cr[5] + cr[6];
        sig[(size_t)b * F_PAD + tid] = s;
    } else if (tid < 64) {
        sig[(size_t)b * F_PAD + F_SIG + (tid - 32)] = 0.f;
    }
}

// ---------- per-feature partial sum / sumsq (no atomics, no init, 4-row ILP) ----------
__global__ void k_stats(const float* __restrict__ sig, float* __restrict__ psum,
                        float* __restrict__ psq) {
    int f = blockIdx.x * 256 + threadIdx.x;
    if (f >= F_SIG) return;
    int y = blockIdx.y;
    const float* sp = sig + (size_t)(y * 64) * F_PAD + f;
    float s = 0.f, q = 0.f;
    for (int r = 0; r < 64; r += 4) {
        float v0 = sp[(size_t)(r + 0) * F_PAD];
        float v1 = sp[(size_t)(r + 1) * F_PAD];
        float v2 = sp[(size_t)(r + 2) * F_PAD];
        float v3 = sp[(size_t)(r + 3) * F_PAD];
        s += v0 + v1 + v2 + v3;
        q = fmaf(v0, v0, q); q = fmaf(v1, v1, q);
        q = fmaf(v2, v2, q); q = fmaf(v3, v3, q);
    }
    psum[(size_t)y * F_PAD + f] = s;
    psq[(size_t)y * F_PAD + f]  = q;
}

// ---------- BN fold (reduces the 32 partials) ----------
__global__ void k_ab(const float* __restrict__ psum, const float* __restrict__ psq,
                     const float* __restrict__ gamma, const float* __restrict__ beta,
                     float* __restrict__ Av, float* __restrict__ Bv) {
    int i = blockIdx.x * 256 + threadIdx.x;
    if (i >= F_PAD) return;
    float a = 0.f, bb = 0.f;
    if (i < F_SIG) {
        float s = 0.f, q = 0.f;
#pragma unroll
        for (int z = 0; z < SY; ++z) {
            s += psum[(size_t)z * F_PAD + i];
            q += psq[(size_t)z * F_PAD + i];
        }
        float m   = s * (1.f / 2048.f);
        float var = q * (1.f / 2048.f) - m * m;
        a  = gamma[i] / sqrtf(var + 1e-5f);
        bb = beta[i] - m * a;
    }
    Av[i] = a;
    Bv[i] = bb;
}

// ---------- reduce partials, fold Av -> WfT; accumulate Bv-dot into bfv ----------
__launch_bounds__(64)
__global__ void k_wfred(const float* __restrict__ part, const float* __restrict__ Av,
                        const float* __restrict__ Bv, float* __restrict__ WfT,
                        float* __restrict__ bfv) {
    const int i = blockIdx.x * 64 + threadIdx.x;
    const int k = blockIdx.y;
    const bool valid = (i < F_SIG) && (k < K_CLS);
    float s = 0.f;
    if (valid) {
#pragma unroll
        for (int z = 0; z < OSPLIT; ++z)
            s += part[((size_t)z * KW_PAD + k) * F_SIG + i];
    }
    if (i < F_SIG)
        WfT[(size_t)i * K_PAD + k] = valid ? Av[i] * s : 0.f;
    // bias contribution: sum_i Bv[i] * S_raw[k,i]
    float pb = valid ? Bv[i] * s : 0.f;
#pragma unroll
    for (int d = 32; d; d >>= 1) pb += __shfl_xor(pb, d);
    if (threadIdx.x == 0 && k < K_CLS) atomicAdd(&bfv[k], pb);
}

// ---------- out[r,k]: 8 rows/block, waves split i-range, W read once per block ----------
__launch_bounds__(256)
__global__ void k_out3(const float* __restrict__ sig, const float* __restrict__ WfT,
                       const float* __restrict__ bf, float* __restrict__ out) {
    __shared__ __align__(16) float slT[F_SIG * 8];   // [i][row] 33.8 KB
    __shared__ __align__(16) float red[4 * 8 * K_PAD]; // 16 KB
    const int tid = threadIdx.x;
    const int r0 = blockIdx.x * 8;
    for (int e = tid; e < 8 * (F_SIG / 4); e += 256) {
        int row = e & 7, c4 = e >> 3;
        float4 v = *reinterpret_cast<const float4*>(sig + (size_t)(r0 + row) * F_PAD + c4 * 4);
        slT[(c4 * 4 + 0) * 8 + row] = v.x;
        slT[(c4 * 4 + 1) * 8 + row] = v.y;
        slT[(c4 * 4 + 2) * 8 + row] = v.z;
        slT[(c4 * 4 + 3) * 8 + row] = v.w;
    }
    __syncthreads();

    const int wv = tid >> 6, lane = tid & 63;
    const int i0 = wv * 264;
    const float2* Wp = reinterpret_cast<const float2*>(WfT) + lane;
    float2 acc[8];
#pragma unroll
    for (int r = 0; r < 8; ++r) acc[r] = make_float2(0.f, 0.f);
    for (int g = 0; g < 33; ++g) {
        const int ib = i0 + g * 8;
        float2 w0 = Wp[(size_t)(ib + 0) * 64];
        float2 w1 = Wp[(size_t)(ib + 1) * 64];
        float2 w2 = Wp[(size_t)(ib + 2) * 64];
        float2 w3 = Wp[(size_t)(ib + 3) * 64];
        float2 w4 = Wp[(size_t)(ib + 4) * 64];
        float2 w5 = Wp[(size_t)(ib + 5) * 64];
        float2 w6 = Wp[(size_t)(ib + 6) * 64];
        float2 w7 = Wp[(size_t)(ib + 7) * 64];
#pragma unroll
        for (int j = 0; j < 8; ++j) {
            float2 wj = (j == 0) ? w0 : (j == 1) ? w1 : (j == 2) ? w2 : (j == 3) ? w3
                      : (j == 4) ? w4 : (j == 5) ? w5 : (j == 6) ? w6 : w7;
            const float4* sp = reinterpret_cast<const float4*>(slT + (ib + j) * 8);
            float4 ra = sp[0], rb = sp[1];
            acc[0].x = fmaf(ra.x, wj.x, acc[0].x); acc[0].y = fmaf(ra.x, wj.y, acc[0].y);
            acc[1].x = fmaf(ra.y, wj.x, acc[1].x); acc[1].y = fmaf(ra.y, wj.y, acc[1].y);
            acc[2].x = fmaf(ra.z, wj.x, acc[2].x); acc[2].y = fmaf(ra.z, wj.y, acc[2].y);
            acc[3].x = fmaf(ra.w, wj.x, acc[3].x); acc[3].y = fmaf(ra.w, wj.y, acc[3].y);
            acc[4].x = fmaf(rb.x, wj.x, acc[4].x); acc[4].y = fmaf(rb.x, wj.y, acc[4].y);
            acc[5].x = fmaf(rb.y, wj.x, acc[5].x); acc[5].y = fmaf(rb.y, wj.y, acc[5].y);
            acc[6].x = fmaf(rb.z, wj.x, acc[6].x); acc[6].y = fmaf(rb.z, wj.y, acc[6].y);
            acc[7].x = fmaf(rb.w, wj.x, acc[7].x); acc[7].y = fmaf(rb.w, wj.y, acc[7].y);
        }
    }
    float2* rp = reinterpret_cast<float2*>(red) + wv * 512 + lane;
#pragma unroll
    for (int r = 0; r < 8; ++r) rp[r * 64] = acc[r];
    __syncthreads();
#pragma unroll
    for (int j = 0; j < 4; ++j) {
        int idx = j * 256 + tid;
        int r = idx >> 7, k = idx & 127;
        float s = red[idx] + red[idx + 1024] + red[idx + 2048] + red[idx + 3072];
        if (k < K_CLS) out[(size_t)(r0 + r) * K_CLS + k] = s + bf[k];
    }
}

extern "C" void kernel_launch(void* const* d_in, const int* in_sizes, int n_in,
                              void* d_out, int out_size, void* d_ws, size_t ws_size,
                              hipStream_t stream) {
    (void)in_sizes; (void)n_in; (void)out_size; (void)ws_size;
    const float* feats = (const float*)d_in[0];
    const float* convw = (const float*)d_in[1];
    const float* gamma = (const float*)d_in[2];
    const float* beta  = (const float*)d_in[3];
    const float* linw  = (const float*)d_in[4];
    const float* linb  = (const float*)d_in[5];
    const float* fcw   = (const float*)d_in[6];
    const float* fcb   = (const float*)d_in[7];
    float* out = (float*)d_out;

    float* ws   = (float*)d_ws;
    float* sig  = ws;                                   // 2048*1088
    float* psum = sig + (size_t)N_B * F_PAD;            // 32*1088
    float* psq  = psum + (size_t)SY * F_PAD;            // 32*1088
    float* Av   = psq + (size_t)SY * F_PAD;             // 1088
    float* Bv   = Av + F_PAD;                           // 1088
    float* part = Bv + F_PAD;                           // 8*112*1056
    float* WfT  = part + (size_t)OSPLIT * KW_PAD * F_SIG;// 1056*128
    float* bfv  = WfT + (size_t)F_SIG * K_PAD;          // 128
    unsigned short* Ahi = (unsigned short*)(bfv + K_PAD);   // 36*512 ushort
    unsigned short* Alo = Ahi + 36 * 512;

    k_wt<<<72, 256, 0, stream>>>(convw, Ahi, Alo);
    k_fused<<<WF_BLKS + BF0_BLKS + N_B, 256, 0, stream>>>(feats, Ahi, Alo, sig,
                                                          fcw, linw, part, linb, fcb, bfv);
    k_stats<<<dim3(5, SY), 256, 0, stream>>>(sig, psum, psq);
    k_ab<<<5, 256, 0, stream>>>(psum, psq, gamma, beta, Av, Bv);
    k_wfred<<<dim3(17, K_PAD), 64, 0, stream>>>(part, Av, Bv, WfT, bfv);
    k_out3<<<N_B / 8, 256, 0, stream>>>(sig, WfT, bfv, out);
}

// Round 11
// 77.711 us; speedup vs baseline: 1.8578x; 1.1228x over previous
//
#include <hip/hip_runtime.h>

#define N_B   2048
#define F_SIG 1056
#define F_PAD 1088
#define K_CLS 100
#define K_PAD 128
#define KW_PAD 112         // k rows allocated in part[] (7 y-blocks x 16)
#define DROW   52          // 49 real + 3 pad, 16B-aligned rows
#define OSPLIT  8
#define OCHUNK 132
#define XW     72          // ushorts per padded-position row (16B-mult, bank-spread)
#define SY     32          // k_stats partial row-groups
#define WF_BLKS 280        // 5 x 7 x 8
#define BF0_BLKS 128

typedef __attribute__((ext_vector_type(8))) short s8v;     // 8 bf16 in 4 VGPRs
typedef __attribute__((ext_vector_type(4))) float f4v;

__device__ __host__ __forceinline__ void split_bf16(float x, unsigned& h, unsigned& l) {
    unsigned u = __builtin_bit_cast(unsigned, x);
    unsigned hb = (u + 0x7FFFu + ((u >> 16) & 1u)) >> 16;
    float hf = __builtin_bit_cast(float, hb << 16);
    float r = x - hf;
    unsigned ur = __builtin_bit_cast(unsigned, r);
    unsigned lb = (ur + 0x7FFFu + ((ur >> 16) & 1u)) >> 16;
    h = hb & 0xFFFFu; l = lb & 0xFFFFu;
}

// ---------- prepack conv weights into MFMA A-fragments (hi/lo split) ----------
__global__ void k_wt(const float* __restrict__ cw, unsigned short* __restrict__ Ahi,
                     unsigned short* __restrict__ Alo) {
    int t = blockIdx.x * 256 + threadIdx.x;
    if (t >= 36 * 512) return;
    int f = t >> 9, r = t & 511, lane = r >> 3, e = r & 7;
    int mt = f & 1, ch = (f >> 1) & 1, tap = f >> 2;
    int oc  = mt * 16 + (lane & 15);
    int cin = ch * 32 + (lane >> 4) * 8 + e;
    float v = cw[oc * 576 + cin * 9 + tap];
    unsigned h, l;
    split_bf16(v, h, l);
    Ahi[t] = (unsigned short)h;
    Alo[t] = (unsigned short)l;
}

#define WF_FMA16(sv, vv) do { \
    A0.x = fmaf((sv).x, (vv).x, A0.x); A0.y = fmaf((sv).x, (vv).y, A0.y); \
    A0.z = fmaf((sv).x, (vv).z, A0.z); A0.w = fmaf((sv).x, (vv).w, A0.w); \
    A1.x = fmaf((sv).y, (vv).x, A1.x); A1.y = fmaf((sv).y, (vv).y, A1.y); \
    A1.z = fmaf((sv).y, (vv).z, A1.z); A1.w = fmaf((sv).y, (vv).w, A1.w); \
    A2.x = fmaf((sv).z, (vv).x, A2.x); A2.y = fmaf((sv).z, (vv).y, A2.y); \
    A2.z = fmaf((sv).z, (vv).z, A2.z); A2.w = fmaf((sv).z, (vv).w, A2.w); \
    A3.x = fmaf((sv).w, (vv).x, A3.x); A3.y = fmaf((sv).w, (vv).y, A3.y); \
    A3.z = fmaf((sv).w, (vv).z, A3.z); A3.w = fmaf((sv).w, (vv).w, A3.w); } while (0)

// ---------- FUSED: [0,280) split-K fcw@lw partials | [280,408) bf0 | [408,2456) conv+sig ----------
// LDS = 28.8 KB only (ysT/Ds/Cs/colS alias the dead x-planes) -> 5 blocks/CU
__launch_bounds__(256, 5)
__global__ void k_fused(const float* __restrict__ x,
                        const unsigned short* __restrict__ Ahi,
                        const unsigned short* __restrict__ Alo,
                        float* __restrict__ sig,
                        const float* __restrict__ fcw, const float* __restrict__ lw,
                        float* __restrict__ part,
                        const float* __restrict__ linb, const float* __restrict__ fcb,
                        float* __restrict__ bfv) {
    __shared__ __align__(16) unsigned short xpl[2][100 * XW];  // 28800 B
    unsigned short* xhi = xpl[0];
    unsigned short* xlo = xpl[1];
    const int tid = threadIdx.x;
    const int bid = blockIdx.x;

    if (bid < WF_BLKS) {
        // ===== k_wf body: part[z][k][i] = sum_{o in chunk z} fcw[k,o]*lin_w[o,i] =====
        const int ibx = bid % 5, ky = (bid / 5) % 7, z = bid / 35;
        const int wv = tid >> 6;
        const int k0 = ky * 16 + wv * 4;
        const int ib = ibx * 256 + (tid & 63) * 4;
        if (ib >= F_SIG) return;
        const float* f0 = fcw + (size_t)min(k0,     K_CLS - 1) * F_SIG;
        const float* f1 = fcw + (size_t)min(k0 + 1, K_CLS - 1) * F_SIG;
        const float* f2 = fcw + (size_t)min(k0 + 2, K_CLS - 1) * F_SIG;
        const float* f3 = fcw + (size_t)min(k0 + 3, K_CLS - 1) * F_SIG;
        const int o0 = z * OCHUNK;
        float4 A0 = {0.f,0.f,0.f,0.f}, A1 = {0.f,0.f,0.f,0.f};
        float4 A2 = {0.f,0.f,0.f,0.f}, A3 = {0.f,0.f,0.f,0.f};
        const float* lwb = lw + (size_t)o0 * F_SIG + ib;
        for (int g = 0; g < OCHUNK / 4; ++g) {
            const int o = o0 + g * 4;
            float4 s0 = *reinterpret_cast<const float4*>(f0 + o);
            float4 s1 = *reinterpret_cast<const float4*>(f1 + o);
            float4 s2 = *reinterpret_cast<const float4*>(f2 + o);
            float4 s3 = *reinterpret_cast<const float4*>(f3 + o);
            const float* lp = lwb + (size_t)(g * 4) * F_SIG;
            float4 v0 = *reinterpret_cast<const float4*>(lp);
            float4 v1 = *reinterpret_cast<const float4*>(lp + F_SIG);
            float4 v2 = *reinterpret_cast<const float4*>(lp + 2 * F_SIG);
            float4 v3 = *reinterpret_cast<const float4*>(lp + 3 * F_SIG);
            float4 sj0 = make_float4(s0.x, s1.x, s2.x, s3.x);
            float4 sj1 = make_float4(s0.y, s1.y, s2.y, s3.y);
            float4 sj2 = make_float4(s0.z, s1.z, s2.z, s3.z);
            float4 sj3 = make_float4(s0.w, s1.w, s2.w, s3.w);
            WF_FMA16(sj0, v0);
            WF_FMA16(sj1, v1);
            WF_FMA16(sj2, v2);
            WF_FMA16(sj3, v3);
        }
        *reinterpret_cast<float4*>(part + ((size_t)z * KW_PAD + k0 + 0) * F_SIG + ib) = A0;
        *reinterpret_cast<float4*>(part + ((size_t)z * KW_PAD + k0 + 1) * F_SIG + ib) = A1;
        *reinterpret_cast<float4*>(part + ((size_t)z * KW_PAD + k0 + 2) * F_SIG + ib) = A2;
        *reinterpret_cast<float4*>(part + ((size_t)z * KW_PAD + k0 + 3) * F_SIG + ib) = A3;
        return;
    }
    if (bid < WF_BLKS + BF0_BLKS) {
        // ===== bf0: bfv[k] = fcb[k] + sum_o fcw[k,o]*lin_b[o]  (rest added by k_wfred) =====
        const int k = bid - WF_BLKS;
        float s = 0.f;
        if (k < K_CLS) {
            const float* fr = fcw + (size_t)k * F_SIG;
            for (int o = tid; o < F_SIG; o += 256) s = fmaf(fr[o], linb[o], s);
        }
#pragma unroll
        for (int d = 32; d; d >>= 1) s += __shfl_xor(s, d);
        float* redf = (float*)xhi;
        if ((tid & 63) == 0) redf[tid >> 6] = s;
        __syncthreads();
        if (tid == 0) {
            float tot = redf[0] + redf[1] + redf[2] + redf[3];
            bfv[k] = (k < K_CLS) ? (tot + fcb[k]) : 0.f;
        }
        return;
    }

    // ===== convsig body =====
    const int b = bid - (WF_BLKS + BF0_BLKS);
    // post-conv aliases inside the (then-dead) x planes:
    float* ysT  = (float*)xpl;          // 64*36 floats = 9216 B
    float* Ds   = ysT + 2304;           // 32*52
    float* Cs   = Ds + 1664;            // 32*52
    float* colS = Cs + 1664;            // 32*8
    {
        unsigned* zh = (unsigned*)xhi;
        unsigned* zl = (unsigned*)xlo;
        for (int e = tid; e < 100 * XW / 2; e += 256) { zh[e] = 0u; zl[e] = 0u; }
    }
    __syncthreads();
    const float4* xb4 = reinterpret_cast<const float4*>(x + (size_t)b * 4096);
    {
        float4 v0 = xb4[tid], v1 = xb4[tid + 256], v2 = xb4[tid + 512], v3 = xb4[tid + 768];
#pragma unroll
        for (int u = 0; u < 4; ++u) {
            float4 v = (u == 0) ? v0 : (u == 1) ? v1 : (u == 2) ? v2 : v3;
            int e = tid + u * 256;
            int cin = e >> 4, p = (e & 15) * 4;
            int ih = p >> 3, iw = p & 7;                   // iw in {0,4}
            int pp = (ih + 1) * 10 + (iw + 1);
            unsigned h, l;
            split_bf16(v.x, h, l); xhi[(pp+0)*XW + cin] = (unsigned short)h; xlo[(pp+0)*XW + cin] = (unsigned short)l;
            split_bf16(v.y, h, l); xhi[(pp+1)*XW + cin] = (unsigned short)h; xlo[(pp+1)*XW + cin] = (unsigned short)l;
            split_bf16(v.z, h, l); xhi[(pp+2)*XW + cin] = (unsigned short)h; xlo[(pp+2)*XW + cin] = (unsigned short)l;
            split_bf16(v.w, h, l); xhi[(pp+3)*XW + cin] = (unsigned short)h; xlo[(pp+3)*XW + cin] = (unsigned short)l;
        }
    }
    __syncthreads();

    // conv: accumulate in registers; ysT written only AFTER x-planes are dead
    f4v acc0 = {0.f, 0.f, 0.f, 0.f};
    f4v acc1 = {0.f, 0.f, 0.f, 0.f};
    int p2_, kg_;
    {
        const int wv = tid >> 6;
        const int lane = tid & 63;
        const int j16 = lane & 15, kg = lane >> 4;
        const int p2 = wv * 16 + j16;
        p2_ = p2; kg_ = kg;
        const int oh = p2 >> 3, ow = p2 & 7;
        const unsigned short* Hb = xhi + (oh * 10 + ow) * XW + kg * 8;
        const unsigned short* Lb = xlo + (oh * 10 + ow) * XW + kg * 8;
        const uint4* AH = reinterpret_cast<const uint4*>(Ahi) + lane;  // frag f at +f*64
        const uint4* AL = reinterpret_cast<const uint4*>(Alo) + lane;
        uint4 a0h = AH[0], a0l = AL[0], a1h = AH[64], a1l = AL[64];
#pragma unroll
        for (int k = 0; k < 18; ++k) {
            const int tap = k >> 1, ch = k & 1;
            const int th = tap / 3, tw = tap % 3;          // fold at compile time
            const int xoff = (th * 10 + tw) * XW + ch * 32;
            uint4 bh = *reinterpret_cast<const uint4*>(Hb + xoff);
            uint4 bl = *reinterpret_cast<const uint4*>(Lb + xoff);
            uint4 n0h, n0l, n1h, n1l;
            if (k < 17) {
                const int kn = k + 1;
                const int fn = ((kn >> 1) * 2 + (kn & 1)) * 2;
                n0h = AH[fn * 64];      n0l = AL[fn * 64];
                n1h = AH[fn * 64 + 64]; n1l = AL[fn * 64 + 64];
            }
            s8v Bh = __builtin_bit_cast(s8v, bh);
            s8v Bl = __builtin_bit_cast(s8v, bl);
            s8v A0h = __builtin_bit_cast(s8v, a0h);
            s8v A0l = __builtin_bit_cast(s8v, a0l);
            s8v A1h = __builtin_bit_cast(s8v, a1h);
            s8v A1l = __builtin_bit_cast(s8v, a1l);
            acc0 = __builtin_amdgcn_mfma_f32_16x16x32_bf16(A0h, Bh, acc0, 0, 0, 0);
            acc0 = __builtin_amdgcn_mfma_f32_16x16x32_bf16(A0h, Bl, acc0, 0, 0, 0);
            acc0 = __builtin_amdgcn_mfma_f32_16x16x32_bf16(A0l, Bh, acc0, 0, 0, 0);
            acc1 = __builtin_amdgcn_mfma_f32_16x16x32_bf16(A1h, Bh, acc1, 0, 0, 0);
            acc1 = __builtin_amdgcn_mfma_f32_16x16x32_bf16(A1h, Bl, acc1, 0, 0, 0);
            acc1 = __builtin_amdgcn_mfma_f32_16x16x32_bf16(A1l, Bh, acc1, 0, 0, 0);
            if (k < 17) { a0h = n0h; a0l = n0l; a1h = n1h; a1l = n1l; }
        }
    }
    __syncthreads();   // all x-plane reads done; planes now dead
    // C/D: col=lane&15 -> pos, row=(lane>>4)*4+reg -> oc
    *reinterpret_cast<f4v*>(ysT + p2_ * 36 + kg_ * 4)      = acc0;
    *reinterpret_cast<f4v*>(ysT + p2_ * 36 + 16 + kg_ * 4) = acc1;
    __syncthreads();

    // fused D + strict column scan; thread = (c, j)
    if (tid < 224) {
        const int c = tid / 7, j = tid - (tid / 7) * 7;
        float a  = ysT[j * 36 + c];
        float bq = ysT[(j + 1) * 36 + c];
        float run = 0.f;
        float* Dc = Ds + c * DROW;
        float* Cc = Cs + c * DROW;
#pragma unroll
        for (int i = 0; i < 7; ++i) {
            float a2 = ysT[((i + 1) * 8 + j) * 36 + c];
            float b2 = ysT[((i + 1) * 8 + j + 1) * 36 + c];
            float d = (b2 - a2) - (bq - a);
            Dc[i * 7 + j] = d;
            Cc[i * 7 + j] = run;
            run += d;
            a = a2; bq = b2;
        }
        colS[c * 8 + j] = run;
    } else {
        const int c = tid - 224;
        Ds[c * DROW + 49] = 0.f; Ds[c * DROW + 50] = 0.f; Ds[c * DROW + 51] = 0.f;
    }
    __syncthreads();

    // in-place strict row scan
    if (tid < 224) {
        const int c = tid / 7, i = tid - (tid / 7) * 7;
        float* Cc = Cs + c * DROW + i * 7;
        float run = 0.f;
#pragma unroll
        for (int j = 0; j < 7; ++j) {
            float v = Cc[j];
            Cc[j] = run;
            run += v;
        }
    } else {
        const int c = tid - 224;
        Cs[c * DROW + 49] = 0.f; Cs[c * DROW + 50] = 0.f; Cs[c * DROW + 51] = 0.f;
    }
    __syncthreads();

    // level-2
    {
        const int bc1 = tid >> 4, bc2 = tid & 15;
        const float* P0 = Cs + bc1 * DROW;
        const float* P1 = Cs + (bc1 + 16) * DROW;
        const float* D0 = Ds + bc2 * DROW;
        const float* D1 = Ds + (bc2 + 16) * DROW;
        float a00 = 0.f, a01 = 0.f, a10 = 0.f, a11 = 0.f;
#pragma unroll
        for (int qb = 0; qb < DROW; qb += 4) {
            float4 p0 = *reinterpret_cast<const float4*>(P0 + qb);
            float4 p1 = *reinterpret_cast<const float4*>(P1 + qb);
            float4 d0 = *reinterpret_cast<const float4*>(D0 + qb);
            float4 d1 = *reinterpret_cast<const float4*>(D1 + qb);
            a00 += p0.x*d0.x + p0.y*d0.y + p0.z*d0.z + p0.w*d0.w;
            a01 += p0.x*d1.x + p0.y*d1.y + p0.z*d1.z + p0.w*d1.w;
            a10 += p1.x*d0.x + p1.y*d0.y + p1.z*d0.z + p1.w*d0.w;
            a11 += p1.x*d1.x + p1.y*d1.y + p1.z*d1.z + p1.w*d1.w;
        }
        float* so = sig + (size_t)b * F_PAD + 32;
        so[bc1 * 32 + bc2]               = a00;
        so[bc1 * 32 + (bc2 + 16)]        = a01;
        so[(bc1 + 16) * 32 + bc2]        = a10;
        so[(bc1 + 16) * 32 + (bc2 + 16)] = a11;
    }

    // level-1 + zero pad
    if (tid < 32) {
        const float* cr = colS + tid * 8;
        float s = cr[0] + cr[1] + cr[2] + cr[3] + cr[4] + cr[5] + cr[6];
        sig[(size_t)b * F_PAD + tid] = s;
    } else if (tid < 64) {
        sig[(size_t)b * F_PAD + F_SIG + (tid - 32)] = 0.f;
    }
}

// ---------- per-feature partial sum / sumsq (no atomics, no init, 4-row ILP) ----------
__global__ void k_stats(const float* __restrict__ sig, float* __restrict__ psum,
                        float* __restrict__ psq) {
    int f = blockIdx.x * 256 + threadIdx.x;
    if (f >= F_SIG) return;
    int y = blockIdx.y;
    const float* sp = sig + (size_t)(y * 64) * F_PAD + f;
    float s = 0.f, q = 0.f;
    for (int r = 0; r < 64; r += 4) {
        float v0 = sp[(size_t)(r + 0) * F_PAD];
        float v1 = sp[(size_t)(r + 1) * F_PAD];
        float v2 = sp[(size_t)(r + 2) * F_PAD];
        float v3 = sp[(size_t)(r + 3) * F_PAD];
        s += v0 + v1 + v2 + v3;
        q = fmaf(v0, v0, q); q = fmaf(v1, v1, q);
        q = fmaf(v2, v2, q); q = fmaf(v3, v3, q);
    }
    psum[(size_t)y * F_PAD + f] = s;
    psq[(size_t)y * F_PAD + f]  = q;
}

// ---------- reduce partials + inline BN fold; WfT + bias accumulation ----------
__launch_bounds__(64)
__global__ void k_wfred(const float* __restrict__ part,
                        const float* __restrict__ psum, const float* __restrict__ psq,
                        const float* __restrict__ gamma, const float* __restrict__ beta,
                        float* __restrict__ WfT, float* __restrict__ bfv) {
    const int i = blockIdx.x * 64 + threadIdx.x;
    const int k = blockIdx.y;
    // inline BN fold (k_ab): Av/Bv recomputed per block -- 64 coalesced lanes x 64 loads
    float a = 0.f, bb = 0.f;
    if (i < F_SIG) {
        float s = 0.f, q = 0.f;
#pragma unroll
        for (int z = 0; z < SY; ++z) {
            s += psum[(size_t)z * F_PAD + i];
            q += psq[(size_t)z * F_PAD + i];
        }
        float m   = s * (1.f / 2048.f);
        float var = q * (1.f / 2048.f) - m * m;
        a  = gamma[i] / sqrtf(var + 1e-5f);
        bb = beta[i] - m * a;
    }
    const bool valid = (i < F_SIG) && (k < K_CLS);
    float s = 0.f;
    if (valid) {
#pragma unroll
        for (int z = 0; z < OSPLIT; ++z)
            s += part[((size_t)z * KW_PAD + k) * F_SIG + i];
    }
    if (i < F_SIG)
        WfT[(size_t)i * K_PAD + k] = valid ? a * s : 0.f;
    // bias contribution: sum_i Bv[i] * S_raw[k,i]
    float pb = valid ? bb * s : 0.f;
#pragma unroll
    for (int d = 32; d; d >>= 1) pb += __shfl_xor(pb, d);
    if (threadIdx.x == 0 && k < K_CLS) atomicAdd(&bfv[k], pb);
}

// ---------- out[r,k]: 8 rows/block, waves split i-range, W read once per block ----------
__launch_bounds__(256)
__global__ void k_out3(const float* __restrict__ sig, const float* __restrict__ WfT,
                       const float* __restrict__ bf, float* __restrict__ out) {
    __shared__ __align__(16) float slT[F_SIG * 8];   // [i][row] 33.8 KB
    __shared__ __align__(16) float red[4 * 8 * K_PAD]; // 16 KB
    const int tid = threadIdx.x;
    const int r0 = blockIdx.x * 8;
    for (int e = tid; e < 8 * (F_SIG / 4); e += 256) {
        int row = e & 7, c4 = e >> 3;
        float4 v = *reinterpret_cast<const float4*>(sig + (size_t)(r0 + row) * F_PAD + c4 * 4);
        slT[(c4 * 4 + 0) * 8 + row] = v.x;
        slT[(c4 * 4 + 1) * 8 + row] = v.y;
        slT[(c4 * 4 + 2) * 8 + row] = v.z;
        slT[(c4 * 4 + 3) * 8 + row] = v.w;
    }
    __syncthreads();

    const int wv = tid >> 6, lane = tid & 63;
    const int i0 = wv * 264;
    const float2* Wp = reinterpret_cast<const float2*>(WfT) + lane;
    float2 acc[8];
#pragma unroll
    for (int r = 0; r < 8; ++r) acc[r] = make_float2(0.f, 0.f);
    for (int g = 0; g < 33; ++g) {
        const int ib = i0 + g * 8;
        float2 w0 = Wp[(size_t)(ib + 0) * 64];
        float2 w1 = Wp[(size_t)(ib + 1) * 64];
        float2 w2 = Wp[(size_t)(ib + 2) * 64];
        float2 w3 = Wp[(size_t)(ib + 3) * 64];
        float2 w4 = Wp[(size_t)(ib + 4) * 64];
        float2 w5 = Wp[(size_t)(ib + 5) * 64];
        float2 w6 = Wp[(size_t)(ib + 6) * 64];
        float2 w7 = Wp[(size_t)(ib + 7) * 64];
#pragma unroll
        for (int j = 0; j < 8; ++j) {
            float2 wj = (j == 0) ? w0 : (j == 1) ? w1 : (j == 2) ? w2 : (j == 3) ? w3
                      : (j == 4) ? w4 : (j == 5) ? w5 : (j == 6) ? w6 : w7;
            const float4* sp = reinterpret_cast<const float4*>(slT + (ib + j) * 8);
            float4 ra = sp[0], rb = sp[1];
            acc[0].x = fmaf(ra.x, wj.x, acc[0].x); acc[0].y = fmaf(ra.x, wj.y, acc[0].y);
            acc[1].x = fmaf(ra.y, wj.x, acc[1].x); acc[1].y = fmaf(ra.y, wj.y, acc[1].y);
            acc[2].x = fmaf(ra.z, wj.x, acc[2].x); acc[2].y = fmaf(ra.z, wj.y, acc[2].y);
            acc[3].x = fmaf(ra.w, wj.x, acc[3].x); acc[3].y = fmaf(ra.w, wj.y, acc[3].y);
            acc[4].x = fmaf(rb.x, wj.x, acc[4].x); acc[4].y = fmaf(rb.x, wj.y, acc[4].y);
            acc[5].x = fmaf(rb.y, wj.x, acc[5].x); acc[5].y = fmaf(rb.y, wj.y, acc[5].y);
            acc[6].x = fmaf(rb.z, wj.x, acc[6].x); acc[6].y = fmaf(rb.z, wj.y, acc[6].y);
            acc[7].x = fmaf(rb.w, wj.x, acc[7].x); acc[7].y = fmaf(rb.w, wj.y, acc[7].y);
        }
    }
    float2* rp = reinterpret_cast<float2*>(red) + wv * 512 + lane;
#pragma unroll
    for (int r = 0; r < 8; ++r) rp[r * 64] = acc[r];
    __syncthreads();
#pragma unroll
    for (int j = 0; j < 4; ++j) {
        int idx = j * 256 + tid;
        int r = idx >> 7, k = idx & 127;
        float s = red[idx] + red[idx + 1024] + red[idx + 2048] + red[idx + 3072];
        if (k < K_CLS) out[(size_t)(r0 + r) * K_CLS + k] = s + bf[k];
    }
}

extern "C" void kernel_launch(void* const* d_in, const int* in_sizes, int n_in,
                              void* d_out, int out_size, void* d_ws, size_t ws_size,
                              hipStream_t stream) {
    (void)in_sizes; (void)n_in; (void)out_size; (void)ws_size;
    const float* feats = (const float*)d_in[0];
    const float* convw = (const float*)d_in[1];
    const float* gamma = (const float*)d_in[2];
    const float* beta  = (const float*)d_in[3];
    const float* linw  = (const float*)d_in[4];
    const float* linb  = (const float*)d_in[5];
    const float* fcw   = (const float*)d_in[6];
    const float* fcb   = (const float*)d_in[7];
    float* out = (float*)d_out;

    float* ws   = (float*)d_ws;
    float* sig  = ws;                                   // 2048*1088
    float* psum = sig + (size_t)N_B * F_PAD;            // 32*1088
    float* psq  = psum + (size_t)SY * F_PAD;            // 32*1088
    float* part = psq + (size_t)SY * F_PAD;             // 8*112*1056
    float* WfT  = part + (size_t)OSPLIT * KW_PAD * F_SIG;// 1056*128
    float* bfv  = WfT + (size_t)F_SIG * K_PAD;          // 128
    unsigned short* Ahi = (unsigned short*)(bfv + K_PAD);   // 36*512 ushort
    unsigned short* Alo = Ahi + 36 * 512;

    k_wt<<<72, 256, 0, stream>>>(convw, Ahi, Alo);
    k_fused<<<WF_BLKS + BF0_BLKS + N_B, 256, 0, stream>>>(feats, Ahi, Alo, sig,
                                                          fcw, linw, part, linb, fcb, bfv);
    k_stats<<<dim3(5, SY), 256, 0, stream>>>(sig, psum, psq);
    k_wfred<<<dim3(17, K_PAD), 64, 0, stream>>>(part, psum, psq, gamma, beta, WfT, bfv);
    k_out3<<<N_B / 8, 256, 0, stream>>>(sig, WfT, bfv, out);
}